// Round 1
// baseline (518.969 us; speedup 1.0000x reference)
//
#include <hip/hip_runtime.h>
#include <hip/hip_bf16.h>

typedef __bf16 bf16;
typedef __attribute__((ext_vector_type(8))) __bf16 bf16x8;
typedef __attribute__((ext_vector_type(4))) __bf16 bf16x4;
typedef __attribute__((ext_vector_type(4))) float f32x4;

#define MFMA16(a, b, c) __builtin_amdgcn_mfma_f32_16x16x32_bf16(a, b, c, 0, 0, 0)

// Problem constants
// B=4, T=2048, C=1024, H=16, D=64, P=64, S=2112

// ---------------------------------------------------------------------------
// Fused QKV projection: O[m,n] = sum_k X[m,k] * W[n,k] + bias[n]
// M=8192, N=1024, K=1024.  blockIdx.z selects Q/K/V.
// Output layout-transformed to bf16 [B,H,T,D] (Q, scale folded) / [B,H,S,D].
// ---------------------------------------------------------------------------
__global__ __launch_bounds__(256) void proj_qkv_gemm(
    const float* __restrict__ X,
    const float* __restrict__ Wq, const float* __restrict__ bq,
    const float* __restrict__ Wk, const float* __restrict__ bk,
    const float* __restrict__ Wv, const float* __restrict__ bv,
    bf16* __restrict__ q_ws, bf16* __restrict__ k_ws, bf16* __restrict__ v_ws)
{
    __shared__ bf16 As[128][32];
    __shared__ bf16 Bs[128][32];
    const int mode = blockIdx.z;
    const float* __restrict__ W    = (mode == 0) ? Wq : (mode == 1) ? Wk : Wv;
    const float* __restrict__ bias = (mode == 0) ? bq : (mode == 1) ? bk : bv;
    const int m0 = blockIdx.x * 128;
    const int n0 = blockIdx.y * 128;
    const int tid  = threadIdx.x;
    const int lane = tid & 63, wave = tid >> 6;
    const int ln = lane & 15, quad = lane >> 4;
    const int wr = (wave >> 1) * 64, wc = (wave & 1) * 64;
    const int srow = tid >> 3;           // 0..31
    const int scol = (tid & 7) * 4;      // float4 column

    const f32x4 z4 = {0.f, 0.f, 0.f, 0.f};
    f32x4 acc[4][4];
#pragma unroll
    for (int i = 0; i < 4; ++i)
#pragma unroll
        for (int j = 0; j < 4; ++j) acc[i][j] = z4;

    for (int k0 = 0; k0 < 1024; k0 += 32) {
        __syncthreads();
#pragma unroll
        for (int r = 0; r < 4; ++r) {
            int row = srow + r * 32;
            float4 a = *(const float4*)&X[(size_t)(m0 + row) * 1024 + k0 + scol];
            float4 w = *(const float4*)&W[(size_t)(n0 + row) * 1024 + k0 + scol];
            bf16x4 ab, wb;
            ab[0] = (bf16)a.x; ab[1] = (bf16)a.y; ab[2] = (bf16)a.z; ab[3] = (bf16)a.w;
            wb[0] = (bf16)w.x; wb[1] = (bf16)w.y; wb[2] = (bf16)w.z; wb[3] = (bf16)w.w;
            *(bf16x4*)&As[row][scol] = ab;
            *(bf16x4*)&Bs[row][scol] = wb;
        }
        __syncthreads();
        bf16x8 af[4], bfr[4];
#pragma unroll
        for (int i = 0; i < 4; ++i) af[i]  = *(const bf16x8*)&As[wr + i * 16 + ln][quad * 8];
#pragma unroll
        for (int j = 0; j < 4; ++j) bfr[j] = *(const bf16x8*)&Bs[wc + j * 16 + ln][quad * 8];
#pragma unroll
        for (int i = 0; i < 4; ++i)
#pragma unroll
            for (int j = 0; j < 4; ++j)
                acc[i][j] = MFMA16(af[i], bfr[j], acc[i][j]);
    }

#pragma unroll
    for (int j = 0; j < 4; ++j) {
        const int n = n0 + wc + j * 16 + ln;
        const float bb = bias[n];
        const int h = n >> 6, d = n & 63;
#pragma unroll
        for (int i = 0; i < 4; ++i) {
#pragma unroll
            for (int r = 0; r < 4; ++r) {
                int m = m0 + wr + i * 16 + quad * 4 + r;
                int b = m >> 11, t = m & 2047;
                float v = acc[i][j][r] + bb;
                if (mode == 0)
                    q_ws[((size_t)(b * 16 + h) * 2048 + t) * 64 + d] = (bf16)(v * 0.125f);
                else if (mode == 1)
                    k_ws[((size_t)(b * 16 + h) * 2112 + 64 + t) * 64 + d] = (bf16)v;
                else
                    v_ws[((size_t)(b * 16 + h) * 2112 + 64 + t) * 64 + d] = (bf16)v;
            }
        }
    }
}

// ---------------------------------------------------------------------------
// Prefix K/V fp32 [B,H,P,D] -> bf16 into k_ws/v_ws slots s in [0,P)
// ---------------------------------------------------------------------------
__global__ __launch_bounds__(256) void prefix_cvt(
    const float* __restrict__ pk, const float* __restrict__ pv,
    bf16* __restrict__ k_ws, bf16* __restrict__ v_ws)
{
    int i = blockIdx.x * 256 + threadIdx.x;   // 0..65535
    int base = i * 4;                          // elem in [0, 262144)
    int bh  = base >> 12;                      // P*D = 4096
    int rem = base & 4095;
    size_t o = (size_t)bh * (2112 * 64) + rem;
    float4 a = *(const float4*)&pk[base];
    bf16x4 ab;
    ab[0] = (bf16)a.x; ab[1] = (bf16)a.y; ab[2] = (bf16)a.z; ab[3] = (bf16)a.w;
    *(bf16x4*)&k_ws[o] = ab;
    float4 v = *(const float4*)&pv[base];
    bf16x4 vb;
    vb[0] = (bf16)v.x; vb[1] = (bf16)v.y; vb[2] = (bf16)v.z; vb[3] = (bf16)v.w;
    *(bf16x4*)&v_ws[o] = vb;
}

// ---------------------------------------------------------------------------
// Flash attention. Block = 4 waves; wave owns 16 query rows (online softmax).
// grid = (T/64, B*H). Mask is key-only; chunk 0 == prefix (always visible).
// ---------------------------------------------------------------------------
__global__ __launch_bounds__(256) void attn_kernel(
    const bf16* __restrict__ Q, const bf16* __restrict__ K,
    const bf16* __restrict__ V, const int* __restrict__ mask,
    bf16* __restrict__ O)
{
    __shared__ bf16 Ks[64][72];        // [s][d], stride padded 64->72
    __shared__ bf16 Vt[64][72];        // [d][s] transposed
    __shared__ bf16 Ps[4][16][72];     // per-wave P tile [m][s]
    __shared__ float mk[64];
    const int tid  = threadIdx.x;
    const int wave = tid >> 6, lane = tid & 63;
    const int ln = lane & 15, quad = lane >> 4;
    const int qt = blockIdx.x, bh = blockIdx.y;
    const int b = bh >> 4, h = bh & 15;
    const bf16* __restrict__ Kb = K + (size_t)bh * (2112 * 64);
    const bf16* __restrict__ Vb = V + (size_t)bh * (2112 * 64);
    const size_t qrow = (size_t)bh * 2048 + qt * 64 + wave * 16;
    const bf16x8 qf0 = *(const bf16x8*)&Q[(qrow + ln) * 64 + quad * 8];
    const bf16x8 qf1 = *(const bf16x8*)&Q[(qrow + ln) * 64 + 32 + quad * 8];

    const f32x4 z4 = {0.f, 0.f, 0.f, 0.f};
    float m_r[4] = {-INFINITY, -INFINITY, -INFINITY, -INFINITY};
    float l_r[4] = {0.f, 0.f, 0.f, 0.f};
    f32x4 acc[4];
    acc[0] = acc[1] = acc[2] = acc[3] = z4;

    const int ks_s = tid >> 3, ks_c = (tid & 7) * 8;   // K staging (coalesced)
    const int vs_s = tid & 31, vs_c = (tid >> 5) * 8;  // V staging (transpose-friendly)

    for (int s0 = 0; s0 < 2112; s0 += 64) {
        __syncthreads();
#pragma unroll
        for (int rr = 0; rr < 2; ++rr) {
            int s = ks_s + rr * 32;
            *(bf16x8*)&Ks[s][ks_c] = *(const bf16x8*)&Kb[(size_t)(s0 + s) * 64 + ks_c];
            int sv = vs_s + rr * 32;
            bf16x8 vv = *(const bf16x8*)&Vb[(size_t)(s0 + sv) * 64 + vs_c];
#pragma unroll
            for (int e = 0; e < 8; ++e) Vt[vs_c + e][sv] = vv[e];
        }
        if (tid < 64) {
            int sg = s0 + tid;
            mk[tid] = (sg < 64) ? 0.f : (mask[b * 2048 + (sg - 64)] != 0 ? 0.f : -1e30f);
        }
        __syncthreads();

        // ---- scores: 16x64 per wave ----
        float sc[4][4];
#pragma unroll
        for (int kt = 0; kt < 4; ++kt) {
            bf16x8 k0 = *(const bf16x8*)&Ks[kt * 16 + ln][quad * 8];
            bf16x8 k1 = *(const bf16x8*)&Ks[kt * 16 + ln][32 + quad * 8];
            f32x4 s4 = z4;
            s4 = MFMA16(qf0, k0, s4);
            s4 = MFMA16(qf1, k1, s4);
            float madd = mk[kt * 16 + ln];
#pragma unroll
            for (int r = 0; r < 4; ++r) sc[kt][r] = s4[r] + madd;
        }

        // ---- online softmax ----
        float mx[4];
#pragma unroll
        for (int r = 0; r < 4; ++r)
            mx[r] = fmaxf(fmaxf(sc[0][r], sc[1][r]), fmaxf(sc[2][r], sc[3][r]));
#pragma unroll
        for (int off = 1; off < 16; off <<= 1)
#pragma unroll
            for (int r = 0; r < 4; ++r)
                mx[r] = fmaxf(mx[r], __shfl_xor(mx[r], off, 16));
        float alpha[4];
#pragma unroll
        for (int r = 0; r < 4; ++r) {
            float mn = fmaxf(m_r[r], mx[r]);
            alpha[r] = __expf(m_r[r] - mn);   // exp(-inf)=0 on first chunk
            m_r[r] = mn;
        }
        float rs[4] = {0.f, 0.f, 0.f, 0.f};
#pragma unroll
        for (int kt = 0; kt < 4; ++kt)
#pragma unroll
            for (int r = 0; r < 4; ++r) {
                float p = __expf(sc[kt][r] - m_r[r]);
                sc[kt][r] = p;
                rs[r] += p;
            }
#pragma unroll
        for (int off = 1; off < 16; off <<= 1)
#pragma unroll
            for (int r = 0; r < 4; ++r)
                rs[r] += __shfl_xor(rs[r], off, 16);
#pragma unroll
        for (int r = 0; r < 4; ++r) l_r[r] = l_r[r] * alpha[r] + rs[r];
#pragma unroll
        for (int j = 0; j < 4; ++j) {
            acc[j][0] *= alpha[0]; acc[j][1] *= alpha[1];
            acc[j][2] *= alpha[2]; acc[j][3] *= alpha[3];
        }

        // ---- P: C-layout -> A-layout via LDS ----
#pragma unroll
        for (int kt = 0; kt < 4; ++kt)
#pragma unroll
            for (int r = 0; r < 4; ++r)
                Ps[wave][quad * 4 + r][kt * 16 + ln] = (bf16)sc[kt][r];
        __syncthreads();

        // ---- PV ----
#pragma unroll
        for (int g = 0; g < 2; ++g) {
            bf16x8 pf = *(const bf16x8*)&Ps[wave][ln][g * 32 + quad * 8];
#pragma unroll
            for (int j = 0; j < 4; ++j) {
                bf16x8 vf = *(const bf16x8*)&Vt[j * 16 + ln][g * 32 + quad * 8];
                acc[j] = MFMA16(pf, vf, acc[j]);
            }
        }
    }

#pragma unroll
    for (int r = 0; r < 4; ++r) {
        float inv = 1.0f / l_r[r];
        int m = qt * 64 + wave * 16 + quad * 4 + r;
#pragma unroll
        for (int j = 0; j < 4; ++j)
            O[((size_t)b * 2048 + m) * 1024 + h * 64 + j * 16 + ln] =
                (bf16)(acc[j][r] * inv);
    }
}

// ---------------------------------------------------------------------------
// Output projection: out[m,n] = sum_k A[m,k]*Wo[n,k] + bo[n]; A bf16, out fp32
// ---------------------------------------------------------------------------
__global__ __launch_bounds__(256) void out_proj_gemm(
    const bf16* __restrict__ A, const float* __restrict__ W,
    const float* __restrict__ bias, float* __restrict__ out)
{
    __shared__ bf16 As[128][32];
    __shared__ bf16 Bs[128][32];
    const int m0 = blockIdx.x * 128, n0 = blockIdx.y * 128;
    const int tid = threadIdx.x;
    const int lane = tid & 63, wave = tid >> 6;
    const int ln = lane & 15, quad = lane >> 4;
    const int wr = (wave >> 1) * 64, wc = (wave & 1) * 64;
    const int srow = tid >> 3, scol = (tid & 7) * 4;
    const int arow = tid >> 2, acol = (tid & 3) * 8;

    const f32x4 z4 = {0.f, 0.f, 0.f, 0.f};
    f32x4 acc[4][4];
#pragma unroll
    for (int i = 0; i < 4; ++i)
#pragma unroll
        for (int j = 0; j < 4; ++j) acc[i][j] = z4;

    for (int k0 = 0; k0 < 1024; k0 += 32) {
        __syncthreads();
#pragma unroll
        for (int rr = 0; rr < 2; ++rr) {
            int row = arow + rr * 64;
            *(bf16x8*)&As[row][acol] =
                *(const bf16x8*)&A[(size_t)(m0 + row) * 1024 + k0 + acol];
        }
#pragma unroll
        for (int r = 0; r < 4; ++r) {
            int row = srow + r * 32;
            float4 w = *(const float4*)&W[(size_t)(n0 + row) * 1024 + k0 + scol];
            bf16x4 wb;
            wb[0] = (bf16)w.x; wb[1] = (bf16)w.y; wb[2] = (bf16)w.z; wb[3] = (bf16)w.w;
            *(bf16x4*)&Bs[row][scol] = wb;
        }
        __syncthreads();
        bf16x8 af[4], bfr[4];
#pragma unroll
        for (int i = 0; i < 4; ++i) af[i]  = *(const bf16x8*)&As[wr + i * 16 + ln][quad * 8];
#pragma unroll
        for (int j = 0; j < 4; ++j) bfr[j] = *(const bf16x8*)&Bs[wc + j * 16 + ln][quad * 8];
#pragma unroll
        for (int i = 0; i < 4; ++i)
#pragma unroll
            for (int j = 0; j < 4; ++j)
                acc[i][j] = MFMA16(af[i], bfr[j], acc[i][j]);
    }

#pragma unroll
    for (int j = 0; j < 4; ++j) {
        const int n = n0 + wc + j * 16 + ln;
        const float bb = bias[n];
#pragma unroll
        for (int i = 0; i < 4; ++i) {
#pragma unroll
            for (int r = 0; r < 4; ++r) {
                int m = m0 + wr + i * 16 + quad * 4 + r;
                out[(size_t)m * 1024 + n] = acc[i][j][r] + bb;
            }
        }
    }
}

// ---------------------------------------------------------------------------
extern "C" void kernel_launch(void* const* d_in, const int* in_sizes, int n_in,
                              void* d_out, int out_size, void* d_ws, size_t ws_size,
                              hipStream_t stream)
{
    const float* x    = (const float*)d_in[0];
    const int*   mask = (const int*)d_in[1];
    const float* pk   = (const float*)d_in[2];
    const float* pv   = (const float*)d_in[3];
    const float* Wq   = (const float*)d_in[4];
    const float* bq   = (const float*)d_in[5];
    const float* Wk   = (const float*)d_in[6];
    const float* bk   = (const float*)d_in[7];
    const float* Wv   = (const float*)d_in[8];
    const float* bv   = (const float*)d_in[9];
    const float* Wo   = (const float*)d_in[10];
    const float* bo   = (const float*)d_in[11];
    float* out = (float*)d_out;

    bf16* q_ws = (bf16*)d_ws;                          // [B,H,T,D]   16 MB
    bf16* k_ws = q_ws + (size_t)8192 * 1024;           // [B,H,S,D]   16.5 MB
    bf16* v_ws = k_ws + (size_t)64 * 2112 * 64;        // [B,H,S,D]   16.5 MB
    bf16* a_ws = v_ws + (size_t)64 * 2112 * 64;        // [B,T,C]     16 MB

    proj_qkv_gemm<<<dim3(64, 8, 3), 256, 0, stream>>>(x, Wq, bq, Wk, bk, Wv, bv,
                                                      q_ws, k_ws, v_ws);
    prefix_cvt<<<dim3(256), 256, 0, stream>>>(pk, pv, k_ws, v_ws);
    attn_kernel<<<dim3(32, 64), 256, 0, stream>>>(q_ws, k_ws, v_ws, mask, a_ws);
    out_proj_gemm<<<dim3(64, 8), 256, 0, stream>>>(a_ws, Wo, bo, out);
}

// Round 2
// 345.792 us; speedup vs baseline: 1.5008x; 1.5008x over previous
//
#include <hip/hip_runtime.h>
#include <hip/hip_bf16.h>

typedef __bf16 bf16;
typedef __attribute__((ext_vector_type(8))) __bf16 bf16x8;
typedef __attribute__((ext_vector_type(4))) __bf16 bf16x4;
typedef __attribute__((ext_vector_type(4))) float f32x4;
typedef __attribute__((ext_vector_type(16))) float f32x16;

#define MFMA16(a, b, c) __builtin_amdgcn_mfma_f32_16x16x32_bf16(a, b, c, 0, 0, 0)
#define MFMA32(a, b, c) __builtin_amdgcn_mfma_f32_32x32x16_bf16(a, b, c, 0, 0, 0)

// async global->LDS, 16B per lane; lds dest must be wave-uniform base
__device__ __forceinline__ void gl_lds16(const void* g, void* l) {
    __builtin_amdgcn_global_load_lds(
        (const __attribute__((address_space(1))) void*)g,
        (__attribute__((address_space(3))) void*)l, 16, 0, 0);
}

// Problem constants: B=4, T=2048, C=1024, H=16, D=64, P=64, S=2112
// Q scale folds 1/sqrt(D) * log2(e) so softmax uses native v_exp_f32 (exp2).
#define QSCALE 0.18033688011f

// ---------------------------------------------------------------------------
// fp32 -> bf16 precast: x (2097152 float4s), Wq/Wk/Wv/Wo (262144 float4s each)
// ---------------------------------------------------------------------------
__global__ __launch_bounds__(256) void cvt_all(
    const float* __restrict__ x, const float* __restrict__ Wq,
    const float* __restrict__ Wk, const float* __restrict__ Wv,
    const float* __restrict__ Wo, bf16* __restrict__ xb, bf16* __restrict__ wb)
{
    int i4 = blockIdx.x * 256 + threadIdx.x;   // 0 .. 3145727
    const float* src; bf16* dst; int off;
    if (i4 < 2097152) { src = x; dst = xb; off = i4; }
    else {
        int j = i4 - 2097152;
        int sel = j >> 18;
        off = j & 262143;
        src = (sel == 0) ? Wq : (sel == 1) ? Wk : (sel == 2) ? Wv : Wo;
        dst = wb + (size_t)sel * 1048576;
    }
    float4 a = *(const float4*)&src[(size_t)off * 4];
    bf16x4 o;
    o[0] = (bf16)a.x; o[1] = (bf16)a.y; o[2] = (bf16)a.z; o[3] = (bf16)a.w;
    *(bf16x4*)&dst[(size_t)off * 4] = o;
}

// ---------------------------------------------------------------------------
// Prefix K/V fp32 [B,H,P,D] -> bf16 into k_ws/v_ws slots s in [0,P)
// ---------------------------------------------------------------------------
__global__ __launch_bounds__(256) void prefix_cvt(
    const float* __restrict__ pk, const float* __restrict__ pv,
    bf16* __restrict__ k_ws, bf16* __restrict__ v_ws)
{
    int i = blockIdx.x * 256 + threadIdx.x;
    int base = i * 4;
    int bh  = base >> 12;
    int rem = base & 4095;
    size_t o = (size_t)bh * (2112 * 64) + rem;
    float4 a = *(const float4*)&pk[base];
    bf16x4 ab;
    ab[0] = (bf16)a.x; ab[1] = (bf16)a.y; ab[2] = (bf16)a.z; ab[3] = (bf16)a.w;
    *(bf16x4*)&k_ws[o] = ab;
    float4 v = *(const float4*)&pv[base];
    bf16x4 vb;
    vb[0] = (bf16)v.x; vb[1] = (bf16)v.y; vb[2] = (bf16)v.z; vb[3] = (bf16)v.w;
    *(bf16x4*)&v_ws[o] = vb;
}

// ---------------------------------------------------------------------------
// Fused QKV projection, bf16 x bf16 (m97 pattern: global_load_lds width 16).
// O[m,n] = sum_k X[m,k]*W[n,k] + bias[n]; epilogue scatters to Q/K/V layouts.
// ---------------------------------------------------------------------------
__global__ __launch_bounds__(256) void proj_qkv_gemm(
    const bf16* __restrict__ X, const bf16* __restrict__ Wb,
    const float* __restrict__ bq, const float* __restrict__ bk,
    const float* __restrict__ bv,
    bf16* __restrict__ q_ws, bf16* __restrict__ k_ws, bf16* __restrict__ v_ws)
{
    __shared__ bf16 As[128 * 32];
    __shared__ bf16 Bs[128 * 32];
    const int mode = blockIdx.z;
    const bf16* __restrict__ W = Wb + (size_t)mode * 1048576;
    const float* __restrict__ bias = (mode == 0) ? bq : (mode == 1) ? bk : bv;
    const int m0 = blockIdx.x * 128, n0 = blockIdx.y * 128;
    const int tid = threadIdx.x, lane = tid & 63, wave = tid >> 6;
    const int ln = lane & 15, quad = lane >> 4;
    const int wr = (wave >> 1) * 64, wc = (wave & 1) * 64;
    const int srow = wave * 32 + (lane >> 2);  // staged row (first of pair)
    const int scol = (lane & 3) * 8;

    const f32x4 z4 = {0.f, 0.f, 0.f, 0.f};
    f32x4 acc[4][4];
#pragma unroll
    for (int i = 0; i < 4; ++i)
#pragma unroll
        for (int j = 0; j < 4; ++j) acc[i][j] = z4;

    for (int k0 = 0; k0 < 1024; k0 += 32) {
        __syncthreads();
        gl_lds16(&X[(size_t)(m0 + srow) * 1024 + k0 + scol],      &As[(wave * 32) * 32]);
        gl_lds16(&X[(size_t)(m0 + srow + 16) * 1024 + k0 + scol], &As[(wave * 32 + 16) * 32]);
        gl_lds16(&W[(size_t)(n0 + srow) * 1024 + k0 + scol],      &Bs[(wave * 32) * 32]);
        gl_lds16(&W[(size_t)(n0 + srow + 16) * 1024 + k0 + scol], &Bs[(wave * 32 + 16) * 32]);
        __syncthreads();
        bf16x8 af[4], bfr[4];
#pragma unroll
        for (int i = 0; i < 4; ++i) af[i]  = *(const bf16x8*)&As[(wr + i * 16 + ln) * 32 + quad * 8];
#pragma unroll
        for (int j = 0; j < 4; ++j) bfr[j] = *(const bf16x8*)&Bs[(wc + j * 16 + ln) * 32 + quad * 8];
#pragma unroll
        for (int i = 0; i < 4; ++i)
#pragma unroll
            for (int j = 0; j < 4; ++j)
                acc[i][j] = MFMA16(af[i], bfr[j], acc[i][j]);
    }

#pragma unroll
    for (int j = 0; j < 4; ++j) {
        const int n = n0 + wc + j * 16 + ln;
        const float bb = bias[n];
        const int h = n >> 6, d = n & 63;
#pragma unroll
        for (int i = 0; i < 4; ++i) {
#pragma unroll
            for (int r = 0; r < 4; ++r) {
                int m = m0 + wr + i * 16 + quad * 4 + r;
                int b = m >> 11, t = m & 2047;
                float v = acc[i][j][r] + bb;
                if (mode == 0)
                    q_ws[((size_t)(b * 16 + h) * 2048 + t) * 64 + d] = (bf16)(v * QSCALE);
                else if (mode == 1)
                    k_ws[((size_t)(b * 16 + h) * 2112 + 64 + t) * 64 + d] = (bf16)v;
                else
                    v_ws[((size_t)(b * 16 + h) * 2112 + 64 + t) * 64 + d] = (bf16)v;
            }
        }
    }
}

// ---------------------------------------------------------------------------
// Flash attention, 32x32x16 MFMA, S^T formulation.
// Block = 4 waves; wave owns 32 queries; chunk = 64 keys.
// grid = (T/128, B*H).  Scores/softmax in log2 domain (scale folded into Q).
// ---------------------------------------------------------------------------
__global__ __launch_bounds__(256) void attn_kernel(
    const bf16* __restrict__ Q, const bf16* __restrict__ K,
    const bf16* __restrict__ V, const int* __restrict__ mask,
    bf16* __restrict__ O)
{
    __shared__ bf16 Ks[64 * 72];       // K chunk [s][d], stride 72 (16B-aligned rows)
    __shared__ bf16 Vt[64 * 72];       // V^T [d][s]
    __shared__ bf16 Ps[4][32 * 72];    // per-wave P^T as [m][s]; reused for O epilogue
    __shared__ float mkv[64];          // additive mask (log2 domain)
    const int tid = threadIdx.x, wave = tid >> 6, lane = tid & 63;
    const int ln = lane & 31, hh = lane >> 5;
    const int bh = blockIdx.y, b = bh >> 4, head = bh & 15;
    const bf16* __restrict__ Kb = K + (size_t)bh * (2112 * 64);
    const bf16* __restrict__ Vb = V + (size_t)bh * (2112 * 64);
    const int qg = blockIdx.x * 128 + wave * 32 + ln;

    bf16x8 qf[4];
#pragma unroll
    for (int kt = 0; kt < 4; ++kt)
        qf[kt] = *(const bf16x8*)&Q[((size_t)bh * 2048 + qg) * 64 + kt * 16 + hh * 8];

    float m_r = -INFINITY, l_r = 0.f;
    f32x16 acc[2];
#pragma unroll
    for (int r = 0; r < 16; ++r) { acc[0][r] = 0.f; acc[1][r] = 0.f; }

    const int ks_s = tid >> 3, ks_c = (tid & 7) * 8;
    const int vs_s = tid & 31, vs_c = (tid >> 5) * 8;

    for (int s0 = 0; s0 < 2112; s0 += 64) {
        __syncthreads();
#pragma unroll
        for (int rr = 0; rr < 2; ++rr) {
            int s = ks_s + rr * 32;
            *(bf16x8*)&Ks[s * 72 + ks_c] = *(const bf16x8*)&Kb[(size_t)(s0 + s) * 64 + ks_c];
            int sv = vs_s + rr * 32;
            bf16x8 vv = *(const bf16x8*)&Vb[(size_t)(s0 + sv) * 64 + vs_c];
#pragma unroll
            for (int e = 0; e < 8; ++e) Vt[(vs_c + e) * 72 + sv] = vv[e];
        }
        if (tid < 64) {
            int sg = s0 + tid;
            mkv[tid] = (sg < 64) ? 0.f : (mask[b * 2048 + (sg - 64)] != 0 ? 0.f : -1e30f);
        }
        __syncthreads();

        // ---- S^T = K * Q^T : two 32s x 32m tiles ----
        f32x16 sc[2];
#pragma unroll
        for (int ts = 0; ts < 2; ++ts) {
            f32x16 s16;
#pragma unroll
            for (int r = 0; r < 16; ++r) s16[r] = 0.f;
#pragma unroll
            for (int kt = 0; kt < 4; ++kt) {
                bf16x8 kf = *(const bf16x8*)&Ks[(ts * 32 + ln) * 72 + kt * 16 + hh * 8];
                s16 = MFMA32(kf, qf[kt], s16);
            }
#pragma unroll
            for (int rg = 0; rg < 4; ++rg) {
                float4 mv = *(const float4*)&mkv[ts * 32 + rg * 8 + hh * 4];
                s16[rg * 4 + 0] += mv.x; s16[rg * 4 + 1] += mv.y;
                s16[rg * 4 + 2] += mv.z; s16[rg * 4 + 3] += mv.w;
            }
            sc[ts] = s16;
        }

        // ---- online softmax (state is scalar per lane: col = query) ----
        float mx = sc[0][0];
#pragma unroll
        for (int r = 1; r < 16; ++r) mx = fmaxf(mx, sc[0][r]);
#pragma unroll
        for (int r = 0; r < 16; ++r) mx = fmaxf(mx, sc[1][r]);
        mx = fmaxf(mx, __shfl_xor(mx, 32));
        float mnew = fmaxf(m_r, mx);
        float alpha = __builtin_amdgcn_exp2f(m_r - mnew);   // 0 on first chunk
        m_r = mnew;

        float rs = 0.f;
#pragma unroll
        for (int ts = 0; ts < 2; ++ts)
#pragma unroll
            for (int rg = 0; rg < 4; ++rg) {
                bf16x4 pb;
#pragma unroll
                for (int i = 0; i < 4; ++i) {
                    float p = __builtin_amdgcn_exp2f(sc[ts][rg * 4 + i] - m_r);
                    rs += p;
                    pb[i] = (bf16)p;
                }
                *(bf16x4*)&Ps[wave][ln * 72 + ts * 32 + rg * 8 + hh * 4] = pb;
            }
        rs += __shfl_xor(rs, 32);
        l_r = l_r * alpha + rs;
        acc[0] *= alpha;
        acc[1] *= alpha;

        __builtin_amdgcn_s_waitcnt(0xC07F);   // lgkmcnt(0): own-wave Ps writes visible

        // ---- O^T += V^T * P ----
        bf16x8 pf[4];
#pragma unroll
        for (int ss = 0; ss < 4; ++ss)
            pf[ss] = *(const bf16x8*)&Ps[wave][ln * 72 + ss * 16 + hh * 8];
#pragma unroll
        for (int ss = 0; ss < 4; ++ss) {
            bf16x8 v0 = *(const bf16x8*)&Vt[ln * 72 + ss * 16 + hh * 8];
            acc[0] = MFMA32(v0, pf[ss], acc[0]);
            bf16x8 v1 = *(const bf16x8*)&Vt[(32 + ln) * 72 + ss * 16 + hh * 8];
            acc[1] = MFMA32(v1, pf[ss], acc[1]);
        }
    }

    // ---- epilogue: normalize, transpose O^T->O via own Ps slice, store ----
    float inv = 1.0f / l_r;
#pragma unroll
    for (int td = 0; td < 2; ++td)
#pragma unroll
        for (int rg = 0; rg < 4; ++rg) {
            bf16x4 ob;
#pragma unroll
            for (int i = 0; i < 4; ++i) ob[i] = (bf16)(acc[td][rg * 4 + i] * inv);
            *(bf16x4*)&Ps[wave][ln * 72 + td * 32 + rg * 8 + hh * 4] = ob;
        }
    __builtin_amdgcn_s_waitcnt(0xC07F);
    const int orow = lane >> 3, oc = (lane & 7) * 8;
#pragma unroll
    for (int pass = 0; pass < 4; ++pass) {
        int ml = pass * 8 + orow;
        bf16x8 ov = *(const bf16x8*)&Ps[wave][ml * 72 + oc];
        int qrow = blockIdx.x * 128 + wave * 32 + ml;
        *(bf16x8*)&O[((size_t)b * 2048 + qrow) * 1024 + head * 64 + oc] = ov;
    }
}

// ---------------------------------------------------------------------------
// Output projection: out[m,n] = sum_k A[m,k]*Wo[n,k] + bo[n]; bf16 in, f32 out
// ---------------------------------------------------------------------------
__global__ __launch_bounds__(256) void out_proj_gemm(
    const bf16* __restrict__ A, const bf16* __restrict__ W,
    const float* __restrict__ bias, float* __restrict__ out)
{
    __shared__ bf16 As[128 * 32];
    __shared__ bf16 Bs[128 * 32];
    const int m0 = blockIdx.x * 128, n0 = blockIdx.y * 128;
    const int tid = threadIdx.x, lane = tid & 63, wave = tid >> 6;
    const int ln = lane & 15, quad = lane >> 4;
    const int wr = (wave >> 1) * 64, wc = (wave & 1) * 64;
    const int srow = wave * 32 + (lane >> 2);
    const int scol = (lane & 3) * 8;

    const f32x4 z4 = {0.f, 0.f, 0.f, 0.f};
    f32x4 acc[4][4];
#pragma unroll
    for (int i = 0; i < 4; ++i)
#pragma unroll
        for (int j = 0; j < 4; ++j) acc[i][j] = z4;

    for (int k0 = 0; k0 < 1024; k0 += 32) {
        __syncthreads();
        gl_lds16(&A[(size_t)(m0 + srow) * 1024 + k0 + scol],      &As[(wave * 32) * 32]);
        gl_lds16(&A[(size_t)(m0 + srow + 16) * 1024 + k0 + scol], &As[(wave * 32 + 16) * 32]);
        gl_lds16(&W[(size_t)(n0 + srow) * 1024 + k0 + scol],      &Bs[(wave * 32) * 32]);
        gl_lds16(&W[(size_t)(n0 + srow + 16) * 1024 + k0 + scol], &Bs[(wave * 32 + 16) * 32]);
        __syncthreads();
        bf16x8 af[4], bfr[4];
#pragma unroll
        for (int i = 0; i < 4; ++i) af[i]  = *(const bf16x8*)&As[(wr + i * 16 + ln) * 32 + quad * 8];
#pragma unroll
        for (int j = 0; j < 4; ++j) bfr[j] = *(const bf16x8*)&Bs[(wc + j * 16 + ln) * 32 + quad * 8];
#pragma unroll
        for (int i = 0; i < 4; ++i)
#pragma unroll
            for (int j = 0; j < 4; ++j)
                acc[i][j] = MFMA16(af[i], bfr[j], acc[i][j]);
    }

#pragma unroll
    for (int j = 0; j < 4; ++j) {
        const int n = n0 + wc + j * 16 + ln;
        const float bb = bias[n];
#pragma unroll
        for (int i = 0; i < 4; ++i) {
#pragma unroll
            for (int r = 0; r < 4; ++r) {
                int m = m0 + wr + i * 16 + quad * 4 + r;
                out[(size_t)m * 1024 + n] = acc[i][j][r] + bb;
            }
        }
    }
}

// ---------------------------------------------------------------------------
extern "C" void kernel_launch(void* const* d_in, const int* in_sizes, int n_in,
                              void* d_out, int out_size, void* d_ws, size_t ws_size,
                              hipStream_t stream)
{
    const float* x    = (const float*)d_in[0];
    const int*   mask = (const int*)d_in[1];
    const float* pk   = (const float*)d_in[2];
    const float* pv   = (const float*)d_in[3];
    const float* Wq   = (const float*)d_in[4];
    const float* bq   = (const float*)d_in[5];
    const float* Wk   = (const float*)d_in[6];
    const float* bk   = (const float*)d_in[7];
    const float* Wv   = (const float*)d_in[8];
    const float* bv   = (const float*)d_in[9];
    const float* Wo   = (const float*)d_in[10];
    const float* bo   = (const float*)d_in[11];
    float* out = (float*)d_out;

    bf16* xb   = (bf16*)d_ws;                    // [8192,1024] bf16 (16.8 MB)
    bf16* wb   = xb + (size_t)8388608;           // 4 x [1024,1024] bf16 (8.4 MB)
    bf16* q_ws = wb + (size_t)4194304;           // [B,H,T,D]
    bf16* k_ws = q_ws + (size_t)8388608;         // [B,H,S,D]
    bf16* v_ws = k_ws + (size_t)8650752;         // [B,H,S,D]
    bf16* a_ws = xb;   // alias: xb fully consumed by proj_qkv before attn writes

    cvt_all<<<dim3(12288), 256, 0, stream>>>(x, Wq, Wk, Wv, Wo, xb, wb);
    prefix_cvt<<<dim3(256), 256, 0, stream>>>(pk, pv, k_ws, v_ws);
    proj_qkv_gemm<<<dim3(64, 8, 3), 256, 0, stream>>>(xb, wb, bq, bk, bv,
                                                      q_ws, k_ws, v_ws);
    attn_kernel<<<dim3(16, 64), 256, 0, stream>>>(q_ws, k_ws, v_ws, mask, a_ws);
    out_proj_gemm<<<dim3(64, 8), 256, 0, stream>>>(a_ws, wb + (size_t)3 * 1048576,
                                                   bo, out);
}

// Round 3
// 318.926 us; speedup vs baseline: 1.6272x; 1.0842x over previous
//
#include <hip/hip_runtime.h>
#include <hip/hip_bf16.h>

typedef __bf16 bf16;
typedef __attribute__((ext_vector_type(8))) __bf16 bf16x8;
typedef __attribute__((ext_vector_type(4))) __bf16 bf16x4;
typedef __attribute__((ext_vector_type(4))) float f32x4;
typedef __attribute__((ext_vector_type(16))) float f32x16;

#define MFMA16(a, b, c) __builtin_amdgcn_mfma_f32_16x16x32_bf16(a, b, c, 0, 0, 0)
#define MFMA32(a, b, c) __builtin_amdgcn_mfma_f32_32x32x16_bf16(a, b, c, 0, 0, 0)

// async global->LDS, 16B per lane; lds dest must be wave-uniform base
__device__ __forceinline__ void gl_lds16(const void* g, void* l) {
    __builtin_amdgcn_global_load_lds(
        (const __attribute__((address_space(1))) void*)g,
        (__attribute__((address_space(3))) void*)l, 16, 0, 0);
}

// Problem constants: B=4, T=2048, C=1024, H=16, D=64, P=64, S=2112
// Q scale folds 1/sqrt(D)*log2(e); softmax uses fixed bias -24 (scores are
// N(0,~1.44) in log2 domain; normalization cancels the bias exactly).
#define QSCALE 0.18033688011f
#define LOGBIAS 24.0f

// ---------------------------------------------------------------------------
// fp32 -> bf16 precast: x (2097152 float4s), Wq/Wk/Wv/Wo (262144 float4s each)
// ---------------------------------------------------------------------------
__global__ __launch_bounds__(256) void cvt_all(
    const float* __restrict__ x, const float* __restrict__ Wq,
    const float* __restrict__ Wk, const float* __restrict__ Wv,
    const float* __restrict__ Wo, bf16* __restrict__ xb, bf16* __restrict__ wb)
{
    int i4 = blockIdx.x * 256 + threadIdx.x;
    const float* src; bf16* dst; int off;
    if (i4 < 2097152) { src = x; dst = xb; off = i4; }
    else {
        int j = i4 - 2097152;
        int sel = j >> 18;
        off = j & 262143;
        src = (sel == 0) ? Wq : (sel == 1) ? Wk : (sel == 2) ? Wv : Wo;
        dst = wb + (size_t)sel * 1048576;
    }
    float4 a = *(const float4*)&src[(size_t)off * 4];
    bf16x4 o;
    o[0] = (bf16)a.x; o[1] = (bf16)a.y; o[2] = (bf16)a.z; o[3] = (bf16)a.w;
    *(bf16x4*)&dst[(size_t)off * 4] = o;
}

// ---------------------------------------------------------------------------
// Prefix K fp32 [B,H,P,D] -> bf16 k_ws[s<P]; prefix V -> TRANSPOSED vt_ws.
// ---------------------------------------------------------------------------
__global__ __launch_bounds__(256) void prefix_cvt(
    const float* __restrict__ pk, const float* __restrict__ pv,
    bf16* __restrict__ k_ws, bf16* __restrict__ vt_ws)
{
    int i = blockIdx.x * 256 + threadIdx.x;     // 0..65535
    // K: 4 consecutive elems along d in [bh][s][d]
    {
        int base = i * 4;
        int bh = base >> 12, rem = base & 4095;
        float4 a = *(const float4*)&pk[base];
        bf16x4 ab;
        ab[0] = (bf16)a.x; ab[1] = (bf16)a.y; ab[2] = (bf16)a.z; ab[3] = (bf16)a.w;
        *(bf16x4*)&k_ws[(size_t)bh * (2112 * 64) + rem] = ab;
    }
    // V^T: thread -> (bh, d, sq); read 4 s at fixed d, write 4 consecutive s
    {
        int bh = i >> 10, r = i & 1023;
        int d = r >> 4, sq = (r & 15) * 4;
        bf16x4 vb;
#pragma unroll
        for (int e = 0; e < 4; ++e)
            vb[e] = (bf16)pv[(size_t)bh * 4096 + (sq + e) * 64 + d];
        *(bf16x4*)&vt_ws[((size_t)bh * 64 + d) * 2112 + sq] = vb;
    }
}

// ---------------------------------------------------------------------------
// Fused QKV projection (m97 pattern). Epilogue scatters:
//   mode0: Q [B,H,T,D] (scaled), mode1: K [B,H,S,D] (+P off),
//   mode2: V^T [B,H,D,S] (+P off) with packed 8B stores.
// ---------------------------------------------------------------------------
__global__ __launch_bounds__(256) void proj_qkv_gemm(
    const bf16* __restrict__ X, const bf16* __restrict__ Wb,
    const float* __restrict__ bq, const float* __restrict__ bk,
    const float* __restrict__ bv,
    bf16* __restrict__ q_ws, bf16* __restrict__ k_ws, bf16* __restrict__ vt_ws)
{
    __shared__ bf16 As[128 * 32];
    __shared__ bf16 Bs[128 * 32];
    const int mode = blockIdx.z;
    const bf16* __restrict__ W = Wb + (size_t)mode * 1048576;
    const float* __restrict__ bias = (mode == 0) ? bq : (mode == 1) ? bk : bv;
    const int m0 = blockIdx.x * 128, n0 = blockIdx.y * 128;
    const int tid = threadIdx.x, lane = tid & 63, wave = tid >> 6;
    const int ln = lane & 15, quad = lane >> 4;
    const int wr = (wave >> 1) * 64, wc = (wave & 1) * 64;
    const int srow = wave * 32 + (lane >> 2);
    const int scol = (lane & 3) * 8;

    const f32x4 z4 = {0.f, 0.f, 0.f, 0.f};
    f32x4 acc[4][4];
#pragma unroll
    for (int i = 0; i < 4; ++i)
#pragma unroll
        for (int j = 0; j < 4; ++j) acc[i][j] = z4;

    for (int k0 = 0; k0 < 1024; k0 += 32) {
        __syncthreads();
        gl_lds16(&X[(size_t)(m0 + srow) * 1024 + k0 + scol],      &As[(wave * 32) * 32]);
        gl_lds16(&X[(size_t)(m0 + srow + 16) * 1024 + k0 + scol], &As[(wave * 32 + 16) * 32]);
        gl_lds16(&W[(size_t)(n0 + srow) * 1024 + k0 + scol],      &Bs[(wave * 32) * 32]);
        gl_lds16(&W[(size_t)(n0 + srow + 16) * 1024 + k0 + scol], &Bs[(wave * 32 + 16) * 32]);
        __syncthreads();
        bf16x8 af[4], bfr[4];
#pragma unroll
        for (int i = 0; i < 4; ++i) af[i]  = *(const bf16x8*)&As[(wr + i * 16 + ln) * 32 + quad * 8];
#pragma unroll
        for (int j = 0; j < 4; ++j) bfr[j] = *(const bf16x8*)&Bs[(wc + j * 16 + ln) * 32 + quad * 8];
#pragma unroll
        for (int i = 0; i < 4; ++i)
#pragma unroll
            for (int j = 0; j < 4; ++j)
                acc[i][j] = MFMA16(af[i], bfr[j], acc[i][j]);
    }

#pragma unroll
    for (int j = 0; j < 4; ++j) {
        const int n = n0 + wc + j * 16 + ln;
        const float bb = bias[n];
        const int h = n >> 6, d = n & 63;
#pragma unroll
        for (int i = 0; i < 4; ++i) {
            int m = m0 + wr + i * 16 + quad * 4;
            int b = m >> 11, t = m & 2047;
            if (mode == 2) {
                bf16x4 pb;
#pragma unroll
                for (int r = 0; r < 4; ++r) pb[r] = (bf16)(acc[i][j][r] + bb);
                *(bf16x4*)&vt_ws[((size_t)(b * 16 + h) * 64 + d) * 2112 + 64 + t] = pb;
            } else if (mode == 0) {
#pragma unroll
                for (int r = 0; r < 4; ++r)
                    q_ws[((size_t)(b * 16 + h) * 2048 + t + r) * 64 + d] =
                        (bf16)((acc[i][j][r] + bb) * QSCALE);
            } else {
#pragma unroll
                for (int r = 0; r < 4; ++r)
                    k_ws[((size_t)(b * 16 + h) * 2112 + 64 + t + r) * 64 + d] =
                        (bf16)(acc[i][j][r] + bb);
            }
        }
    }
}

// ---------------------------------------------------------------------------
// Flash attention, 32x32x16 MFMA, S^T form, fixed-bias softmax (no running
// max / rescale). Block = 4 waves x 32 queries; chunk = 64 keys.
// ---------------------------------------------------------------------------
__global__ __launch_bounds__(256) void attn_kernel(
    const bf16* __restrict__ Q, const bf16* __restrict__ K,
    const bf16* __restrict__ VT, const int* __restrict__ mask,
    bf16* __restrict__ O)
{
    __shared__ bf16 Ks[64 * 72];       // K chunk [s][d], stride 72
    __shared__ bf16 Vt[64 * 72];       // V^T chunk [d][s], stride 72
    __shared__ bf16 Ps[4][32 * 72];    // per-wave P^T [q][s]; reused in epilogue
    __shared__ float mkv[64];          // -24 (visible) / -1e30 (masked)
    const int tid = threadIdx.x, wave = tid >> 6, lane = tid & 63;
    const int ln = lane & 31, hh = lane >> 5;
    const int bh = blockIdx.y, b = bh >> 4, head = bh & 15;
    const bf16* __restrict__ Kb  = K  + (size_t)bh * (2112 * 64);
    const bf16* __restrict__ Vtb = VT + (size_t)bh * (64 * 2112);
    const int qg = blockIdx.x * 128 + wave * 32 + ln;

    bf16x8 qf[4];
#pragma unroll
    for (int kt = 0; kt < 4; ++kt)
        qf[kt] = *(const bf16x8*)&Q[((size_t)bh * 2048 + qg) * 64 + kt * 16 + hh * 8];

    float l_r = 0.f;
    f32x16 acc[2];
#pragma unroll
    for (int r = 0; r < 16; ++r) { acc[0][r] = 0.f; acc[1][r] = 0.f; }

    const int ks_s = tid >> 3, ks_c = (tid & 7) * 8;   // K stage: 32 s x 64 d
    const int vd = tid >> 3,  vs = (tid & 7) * 8;      // V stage: 32 d x 64 s

    // ---- prefetch chunk 0 into registers ----
    bf16x8 kr0, kr1, vr0, vr1;
    int mreg = 0;
    {
        const int s0 = 0;
        kr0 = *(const bf16x8*)&Kb[(size_t)(s0 + ks_s) * 64 + ks_c];
        kr1 = *(const bf16x8*)&Kb[(size_t)(s0 + ks_s + 32) * 64 + ks_c];
        vr0 = *(const bf16x8*)&Vtb[(size_t)vd * 2112 + s0 + vs];
        vr1 = *(const bf16x8*)&Vtb[(size_t)(vd + 32) * 2112 + s0 + vs];
        if (wave == 0) {
            int sg = s0 + lane, idx = sg - 64; if (idx < 0) idx = 0;
            int mv = mask[b * 2048 + idx];
            mreg = (sg < 64) ? 1 : mv;
        }
    }

    for (int s0 = 0; s0 < 2112; s0 += 64) {
        __syncthreads();
        *(bf16x8*)&Ks[ks_s * 72 + ks_c]        = kr0;
        *(bf16x8*)&Ks[(ks_s + 32) * 72 + ks_c] = kr1;
        *(bf16x8*)&Vt[vd * 72 + vs]            = vr0;
        *(bf16x8*)&Vt[(vd + 32) * 72 + vs]     = vr1;
        if (wave == 0) mkv[lane] = mreg ? -LOGBIAS : -1e30f;
        __syncthreads();

        // ---- prefetch next chunk ----
        if (s0 + 64 < 2112) {
            const int sn = s0 + 64;
            kr0 = *(const bf16x8*)&Kb[(size_t)(sn + ks_s) * 64 + ks_c];
            kr1 = *(const bf16x8*)&Kb[(size_t)(sn + ks_s + 32) * 64 + ks_c];
            vr0 = *(const bf16x8*)&Vtb[(size_t)vd * 2112 + sn + vs];
            vr1 = *(const bf16x8*)&Vtb[(size_t)(vd + 32) * 2112 + sn + vs];
            if (wave == 0) {
                int sg = sn + lane, idx = sg - 64; if (idx < 0) idx = 0;
                int mv = mask[b * 2048 + idx];
                mreg = (sg < 64) ? 1 : mv;
            }
        }

        // ---- scores + exp2 + P write (no running max) ----
        float rs = 0.f;
#pragma unroll
        for (int ts = 0; ts < 2; ++ts) {
            f32x16 s16;
#pragma unroll
            for (int r = 0; r < 16; ++r) s16[r] = 0.f;
#pragma unroll
            for (int kt = 0; kt < 4; ++kt) {
                bf16x8 kf = *(const bf16x8*)&Ks[(ts * 32 + ln) * 72 + kt * 16 + hh * 8];
                s16 = MFMA32(kf, qf[kt], s16);
            }
#pragma unroll
            for (int rg = 0; rg < 4; ++rg) {
                float4 mv = *(const float4*)&mkv[ts * 32 + rg * 8 + hh * 4];
                bf16x4 pb;
                float p0 = __builtin_amdgcn_exp2f(s16[rg * 4 + 0] + mv.x);
                float p1 = __builtin_amdgcn_exp2f(s16[rg * 4 + 1] + mv.y);
                float p2 = __builtin_amdgcn_exp2f(s16[rg * 4 + 2] + mv.z);
                float p3 = __builtin_amdgcn_exp2f(s16[rg * 4 + 3] + mv.w);
                rs += p0 + p1 + p2 + p3;
                pb[0] = (bf16)p0; pb[1] = (bf16)p1; pb[2] = (bf16)p2; pb[3] = (bf16)p3;
                *(bf16x4*)&Ps[wave][ln * 72 + ts * 32 + rg * 8 + hh * 4] = pb;
            }
        }
        l_r += rs;

        __builtin_amdgcn_s_waitcnt(0xC07F);   // lgkmcnt(0): own Ps writes visible

        // ---- O^T += V^T * P ----
        bf16x8 pf[4];
#pragma unroll
        for (int ss = 0; ss < 4; ++ss)
            pf[ss] = *(const bf16x8*)&Ps[wave][ln * 72 + ss * 16 + hh * 8];
#pragma unroll
        for (int ss = 0; ss < 4; ++ss) {
            bf16x8 v0 = *(const bf16x8*)&Vt[ln * 72 + ss * 16 + hh * 8];
            acc[0] = MFMA32(v0, pf[ss], acc[0]);
            bf16x8 v1 = *(const bf16x8*)&Vt[(32 + ln) * 72 + ss * 16 + hh * 8];
            acc[1] = MFMA32(v1, pf[ss], acc[1]);
        }
    }

    // ---- epilogue: combine l across hh halves, normalize, transpose, store ----
    l_r += __shfl_xor(l_r, 32);
    float inv = 1.0f / l_r;
#pragma unroll
    for (int td = 0; td < 2; ++td)
#pragma unroll
        for (int rg = 0; rg < 4; ++rg) {
            bf16x4 ob;
#pragma unroll
            for (int i = 0; i < 4; ++i) ob[i] = (bf16)(acc[td][rg * 4 + i] * inv);
            *(bf16x4*)&Ps[wave][ln * 72 + td * 32 + rg * 8 + hh * 4] = ob;
        }
    __builtin_amdgcn_s_waitcnt(0xC07F);
    const int orow = lane >> 3, oc = (lane & 7) * 8;
#pragma unroll
    for (int pass = 0; pass < 4; ++pass) {
        int ml = pass * 8 + orow;
        bf16x8 ov = *(const bf16x8*)&Ps[wave][ml * 72 + oc];
        int qrow = blockIdx.x * 128 + wave * 32 + ml;
        *(bf16x8*)&O[((size_t)b * 2048 + qrow) * 1024 + head * 64 + oc] = ov;
    }
}

// ---------------------------------------------------------------------------
// Output projection: out[m,n] = sum_k A[m,k]*Wo[n,k] + bo[n]; bf16 in, f32 out
// ---------------------------------------------------------------------------
__global__ __launch_bounds__(256) void out_proj_gemm(
    const bf16* __restrict__ A, const bf16* __restrict__ W,
    const float* __restrict__ bias, float* __restrict__ out)
{
    __shared__ bf16 As[128 * 32];
    __shared__ bf16 Bs[128 * 32];
    const int m0 = blockIdx.x * 128, n0 = blockIdx.y * 128;
    const int tid = threadIdx.x, lane = tid & 63, wave = tid >> 6;
    const int ln = lane & 15, quad = lane >> 4;
    const int wr = (wave >> 1) * 64, wc = (wave & 1) * 64;
    const int srow = wave * 32 + (lane >> 2);
    const int scol = (lane & 3) * 8;

    const f32x4 z4 = {0.f, 0.f, 0.f, 0.f};
    f32x4 acc[4][4];
#pragma unroll
    for (int i = 0; i < 4; ++i)
#pragma unroll
        for (int j = 0; j < 4; ++j) acc[i][j] = z4;

    for (int k0 = 0; k0 < 1024; k0 += 32) {
        __syncthreads();
        gl_lds16(&A[(size_t)(m0 + srow) * 1024 + k0 + scol],      &As[(wave * 32) * 32]);
        gl_lds16(&A[(size_t)(m0 + srow + 16) * 1024 + k0 + scol], &As[(wave * 32 + 16) * 32]);
        gl_lds16(&W[(size_t)(n0 + srow) * 1024 + k0 + scol],      &Bs[(wave * 32) * 32]);
        gl_lds16(&W[(size_t)(n0 + srow + 16) * 1024 + k0 + scol], &Bs[(wave * 32 + 16) * 32]);
        __syncthreads();
        bf16x8 af[4], bfr[4];
#pragma unroll
        for (int i = 0; i < 4; ++i) af[i]  = *(const bf16x8*)&As[(wr + i * 16 + ln) * 32 + quad * 8];
#pragma unroll
        for (int j = 0; j < 4; ++j) bfr[j] = *(const bf16x8*)&Bs[(wc + j * 16 + ln) * 32 + quad * 8];
#pragma unroll
        for (int i = 0; i < 4; ++i)
#pragma unroll
            for (int j = 0; j < 4; ++j)
                acc[i][j] = MFMA16(af[i], bfr[j], acc[i][j]);
    }

#pragma unroll
    for (int j = 0; j < 4; ++j) {
        const int n = n0 + wc + j * 16 + ln;
        const float bb = bias[n];
#pragma unroll
        for (int i = 0; i < 4; ++i) {
#pragma unroll
            for (int r = 0; r < 4; ++r) {
                int m = m0 + wr + i * 16 + quad * 4 + r;
                out[(size_t)m * 1024 + n] = acc[i][j][r] + bb;
            }
        }
    }
}

// ---------------------------------------------------------------------------
extern "C" void kernel_launch(void* const* d_in, const int* in_sizes, int n_in,
                              void* d_out, int out_size, void* d_ws, size_t ws_size,
                              hipStream_t stream)
{
    const float* x    = (const float*)d_in[0];
    const int*   mask = (const int*)d_in[1];
    const float* pk   = (const float*)d_in[2];
    const float* pv   = (const float*)d_in[3];
    const float* Wq   = (const float*)d_in[4];
    const float* bq   = (const float*)d_in[5];
    const float* Wk   = (const float*)d_in[6];
    const float* bk   = (const float*)d_in[7];
    const float* Wv   = (const float*)d_in[8];
    const float* bv   = (const float*)d_in[9];
    const float* Wo   = (const float*)d_in[10];
    const float* bo   = (const float*)d_in[11];
    float* out = (float*)d_out;

    bf16* xb    = (bf16*)d_ws;                   // [8192,1024] bf16
    bf16* wb    = xb + (size_t)8388608;          // 4 x [1024,1024] bf16
    bf16* q_ws  = wb + (size_t)4194304;          // [B,H,T,D]
    bf16* k_ws  = q_ws + (size_t)8388608;        // [B,H,S,D]
    bf16* vt_ws = k_ws + (size_t)8650752;        // [B,H,D,S] (transposed V)
    bf16* a_ws  = xb;   // alias: xb consumed by proj_qkv before attn writes

    cvt_all<<<dim3(12288), 256, 0, stream>>>(x, Wq, Wk, Wv, Wo, xb, wb);
    prefix_cvt<<<dim3(256), 256, 0, stream>>>(pk, pv, k_ws, vt_ws);
    proj_qkv_gemm<<<dim3(64, 8, 3), 256, 0, stream>>>(xb, wb, bq, bk, bv,
                                                      q_ws, k_ws, vt_ws);
    attn_kernel<<<dim3(16, 64), 256, 0, stream>>>(q_ws, k_ws, vt_ws, mask, a_ws);
    out_proj_gemm<<<dim3(64, 8), 256, 0, stream>>>(a_ws, wb + (size_t)3 * 1048576,
                                                   bo, out);
}

// Round 4
// 283.327 us; speedup vs baseline: 1.8317x; 1.1256x over previous
//
#include <hip/hip_runtime.h>
#include <hip/hip_bf16.h>

typedef __bf16 bf16;
typedef __attribute__((ext_vector_type(8))) __bf16 bf16x8;
typedef __attribute__((ext_vector_type(4))) __bf16 bf16x4;
typedef __attribute__((ext_vector_type(4))) float f32x4;
typedef __attribute__((ext_vector_type(16))) float f32x16;

#define MFMA16(a, b, c) __builtin_amdgcn_mfma_f32_16x16x32_bf16(a, b, c, 0, 0, 0)
#define MFMA32(a, b, c) __builtin_amdgcn_mfma_f32_32x32x16_bf16(a, b, c, 0, 0, 0)

__device__ __forceinline__ void gl_lds16(const void* g, void* l) {
    __builtin_amdgcn_global_load_lds(
        (const __attribute__((address_space(1))) void*)g,
        (__attribute__((address_space(3))) void*)l, 16, 0, 0);
}

// Problem constants: B=4, T=2048, C=1024, H=16, D=64, P=64, S=2112
// Q scale folds 1/sqrt(D)*log2(e); softmax uses fixed bias -24 (scores are
// N(0,~1.44) in log2 domain; the bias cancels in normalization exactly).
#define QSCALE 0.18033688011f
#define LOGBIAS 24.0f

// ---------------------------------------------------------------------------
// fp32 -> bf16 precast: x (2097152 float4s), Wq/Wk/Wv/Wo (262144 float4s each)
// ---------------------------------------------------------------------------
__global__ __launch_bounds__(256) void cvt_all(
    const float* __restrict__ x, const float* __restrict__ Wq,
    const float* __restrict__ Wk, const float* __restrict__ Wv,
    const float* __restrict__ Wo, bf16* __restrict__ xb, bf16* __restrict__ wb)
{
    int i4 = blockIdx.x * 256 + threadIdx.x;
    const float* src; bf16* dst; int off;
    if (i4 < 2097152) { src = x; dst = xb; off = i4; }
    else {
        int j = i4 - 2097152;
        int sel = j >> 18;
        off = j & 262143;
        src = (sel == 0) ? Wq : (sel == 1) ? Wk : (sel == 2) ? Wv : Wo;
        dst = wb + (size_t)sel * 1048576;
    }
    float4 a = *(const float4*)&src[(size_t)off * 4];
    bf16x4 o;
    o[0] = (bf16)a.x; o[1] = (bf16)a.y; o[2] = (bf16)a.z; o[3] = (bf16)a.w;
    *(bf16x4*)&dst[(size_t)off * 4] = o;
}

// ---------------------------------------------------------------------------
// Per-batch mask scan: slot[b][t] = 64 + (#visible t'<t) if visible else -1;
// nk[b] = 64 + #visible.  One block (256 thr) per batch, 8 elems/thread.
// ---------------------------------------------------------------------------
__global__ __launch_bounds__(256) void mask_scan(
    const int* __restrict__ mask, int* __restrict__ slot, int* __restrict__ nk)
{
    const int b = blockIdx.x, tid = threadIdx.x;
    const int lane = tid & 63, wv = tid >> 6;
    const int* mb = mask + b * 2048;
    int loc[8], s = 0;
#pragma unroll
    for (int e = 0; e < 8; ++e) { loc[e] = (mb[tid * 8 + e] != 0); s += loc[e]; }
    int inc = s;
#pragma unroll
    for (int off = 1; off < 64; off <<= 1) {
        int t = __shfl_up(inc, off);
        if (lane >= off) inc += t;
    }
    __shared__ int wt[4];
    if (lane == 63) wt[wv] = inc;
    __syncthreads();
    int wo = 0;
    for (int w = 0; w < wv; ++w) wo += wt[w];
    int excl = wo + inc - s;
#pragma unroll
    for (int e = 0; e < 8; ++e) {
        slot[b * 2048 + tid * 8 + e] = loc[e] ? (64 + excl) : -1;
        excl += loc[e];
    }
    if (tid == 255) nk[b] = 64 + wo + inc;
}

// ---------------------------------------------------------------------------
// Prefix K fp32 [B,H,P,D] -> bf16 k_ws slots [0,P); prefix V -> vt_ws (V^T).
// ---------------------------------------------------------------------------
__global__ __launch_bounds__(256) void prefix_cvt(
    const float* __restrict__ pk, const float* __restrict__ pv,
    bf16* __restrict__ k_ws, bf16* __restrict__ vt_ws)
{
    int i = blockIdx.x * 256 + threadIdx.x;     // 0..65535
    {
        int base = i * 4;
        int bh = base >> 12, rem = base & 4095;
        float4 a = *(const float4*)&pk[base];
        bf16x4 ab;
        ab[0] = (bf16)a.x; ab[1] = (bf16)a.y; ab[2] = (bf16)a.z; ab[3] = (bf16)a.w;
        *(bf16x4*)&k_ws[(size_t)bh * (2112 * 64) + rem] = ab;
    }
    {
        int bh = i >> 10, r = i & 1023;
        int d = r >> 4, sq = (r & 15) * 4;
        bf16x4 vb;
#pragma unroll
        for (int e = 0; e < 4; ++e)
            vb[e] = (bf16)pv[(size_t)bh * 4096 + (sq + e) * 64 + d];
        *(bf16x4*)&vt_ws[((size_t)bh * 64 + d) * 2112 + sq] = vb;
    }
}

// ---------------------------------------------------------------------------
// Fused QKV projection (m97 pattern).  Epilogue:
//   mode0: Q [B,H,T,D] (scaled); mode1: K compacted via slot[]; mode2: V^T
//   [B,H,D,Svis] compacted via slot[].  Masked keys are never written.
// ---------------------------------------------------------------------------
__global__ __launch_bounds__(256) void proj_qkv_gemm(
    const bf16* __restrict__ X, const bf16* __restrict__ Wb,
    const float* __restrict__ bq, const float* __restrict__ bk,
    const float* __restrict__ bv, const int* __restrict__ slot,
    bf16* __restrict__ q_ws, bf16* __restrict__ k_ws, bf16* __restrict__ vt_ws)
{
    __shared__ bf16 As[128 * 32];
    __shared__ bf16 Bs[128 * 32];
    const int mode = blockIdx.z;
    const bf16* __restrict__ W = Wb + (size_t)mode * 1048576;
    const float* __restrict__ bias = (mode == 0) ? bq : (mode == 1) ? bk : bv;
    const int m0 = blockIdx.x * 128, n0 = blockIdx.y * 128;
    const int tid = threadIdx.x, lane = tid & 63, wave = tid >> 6;
    const int ln = lane & 15, quad = lane >> 4;
    const int wr = (wave >> 1) * 64, wc = (wave & 1) * 64;
    const int srow = wave * 32 + (lane >> 2);
    const int scol = (lane & 3) * 8;

    const f32x4 z4 = {0.f, 0.f, 0.f, 0.f};
    f32x4 acc[4][4];
#pragma unroll
    for (int i = 0; i < 4; ++i)
#pragma unroll
        for (int j = 0; j < 4; ++j) acc[i][j] = z4;

    for (int k0 = 0; k0 < 1024; k0 += 32) {
        __syncthreads();
        gl_lds16(&X[(size_t)(m0 + srow) * 1024 + k0 + scol],      &As[(wave * 32) * 32]);
        gl_lds16(&X[(size_t)(m0 + srow + 16) * 1024 + k0 + scol], &As[(wave * 32 + 16) * 32]);
        gl_lds16(&W[(size_t)(n0 + srow) * 1024 + k0 + scol],      &Bs[(wave * 32) * 32]);
        gl_lds16(&W[(size_t)(n0 + srow + 16) * 1024 + k0 + scol], &Bs[(wave * 32 + 16) * 32]);
        __syncthreads();
        bf16x8 af[4], bfr[4];
#pragma unroll
        for (int i = 0; i < 4; ++i) af[i]  = *(const bf16x8*)&As[(wr + i * 16 + ln) * 32 + quad * 8];
#pragma unroll
        for (int j = 0; j < 4; ++j) bfr[j] = *(const bf16x8*)&Bs[(wc + j * 16 + ln) * 32 + quad * 8];
#pragma unroll
        for (int i = 0; i < 4; ++i)
#pragma unroll
            for (int j = 0; j < 4; ++j)
                acc[i][j] = MFMA16(af[i], bfr[j], acc[i][j]);
    }

    if (mode == 0) {
#pragma unroll
        for (int j = 0; j < 4; ++j) {
            const int n = n0 + wc + j * 16 + ln;
            const float bb = bias[n];
            const int h = n >> 6, d = n & 63;
#pragma unroll
            for (int i = 0; i < 4; ++i) {
                int m = m0 + wr + i * 16 + quad * 4;
                int b = m >> 11, t = m & 2047;
#pragma unroll
                for (int r = 0; r < 4; ++r)
                    q_ws[((size_t)(b * 16 + h) * 2048 + t + r) * 64 + d] =
                        (bf16)((acc[i][j][r] + bb) * QSCALE);
            }
        }
    } else {
        // compacted slots for this thread's 16 t values (m-dependent only)
        int sl[4][4];
        {
            int m = m0 + wr + quad * 4;
            int b = m >> 11;
#pragma unroll
            for (int i = 0; i < 4; ++i) {
                int t = (m + i * 16) & 2047;
#pragma unroll
                for (int r = 0; r < 4; ++r)
                    sl[i][r] = slot[b * 2048 + t + r];
            }
        }
        const int bsel = (m0 + wr) >> 11;
#pragma unroll
        for (int j = 0; j < 4; ++j) {
            const int n = n0 + wc + j * 16 + ln;
            const float bb = bias[n];
            const int h = n >> 6, d = n & 63;
            const size_t bh64 = (size_t)(bsel * 16 + h);
#pragma unroll
            for (int i = 0; i < 4; ++i) {
#pragma unroll
                for (int r = 0; r < 4; ++r) {
                    int s = sl[i][r];
                    if (s >= 0) {
                        bf16 v = (bf16)(acc[i][j][r] + bb);
                        if (mode == 1)
                            k_ws[(bh64 * 2112 + s) * 64 + d] = v;
                        else
                            vt_ws[(bh64 * 64 + d) * 2112 + s] = v;
                    }
                }
            }
        }
    }
}

// ---------------------------------------------------------------------------
// Flash attention over COMPACTED keys (nkeys = 64 + nvis per batch).
// 32x32x16 MFMA, S^T form, fixed-bias softmax.  Block = 4 waves x 32 queries.
// Last partial chunk: slots >= nkeys get -1e30 (poisoned K is a denormal,
// not NaN; exp2 -> exact 0; V contribution 0).
// ---------------------------------------------------------------------------
__global__ __launch_bounds__(256) void attn_kernel(
    const bf16* __restrict__ Q, const bf16* __restrict__ K,
    const bf16* __restrict__ VT, const int* __restrict__ nk,
    bf16* __restrict__ O)
{
    __shared__ bf16 Ks[64 * 72];
    __shared__ bf16 Vt[64 * 72];
    __shared__ bf16 Ps[4][32 * 72];
    const int tid = threadIdx.x, wave = tid >> 6, lane = tid & 63;
    const int ln = lane & 31, hh = lane >> 5;
    const int bh = blockIdx.y, b = bh >> 4, head = bh & 15;
    const bf16* __restrict__ Kb  = K  + (size_t)bh * (2112 * 64);
    const bf16* __restrict__ Vtb = VT + (size_t)bh * (64 * 2112);
    const int qg = blockIdx.x * 128 + wave * 32 + ln;
    const int nkeys = nk[b];
    const int send = ((nkeys + 63) >> 6) << 6;

    bf16x8 qf[4];
#pragma unroll
    for (int kt = 0; kt < 4; ++kt)
        qf[kt] = *(const bf16x8*)&Q[((size_t)bh * 2048 + qg) * 64 + kt * 16 + hh * 8];

    float l_r = 0.f;
    f32x16 acc[2];
#pragma unroll
    for (int r = 0; r < 16; ++r) { acc[0][r] = 0.f; acc[1][r] = 0.f; }

    const int ks_s = tid >> 3, ks_c = (tid & 7) * 8;   // K stage: 32 s x 64 d
    const int vd = tid >> 3,  vs = (tid & 7) * 8;      // V stage: 32 d x 64 s

    bf16x8 kr0, kr1, vr0, vr1;
    kr0 = *(const bf16x8*)&Kb[(size_t)ks_s * 64 + ks_c];
    kr1 = *(const bf16x8*)&Kb[(size_t)(ks_s + 32) * 64 + ks_c];
    vr0 = *(const bf16x8*)&Vtb[(size_t)vd * 2112 + vs];
    vr1 = *(const bf16x8*)&Vtb[(size_t)(vd + 32) * 2112 + vs];

    for (int s0 = 0; s0 < send; s0 += 64) {
        __syncthreads();
        *(bf16x8*)&Ks[ks_s * 72 + ks_c]        = kr0;
        *(bf16x8*)&Ks[(ks_s + 32) * 72 + ks_c] = kr1;
        *(bf16x8*)&Vt[vd * 72 + vs]            = vr0;
        *(bf16x8*)&Vt[(vd + 32) * 72 + vs]     = vr1;
        __syncthreads();

        if (s0 + 64 < send) {
            const int sn = s0 + 64;
            kr0 = *(const bf16x8*)&Kb[(size_t)(sn + ks_s) * 64 + ks_c];
            kr1 = *(const bf16x8*)&Kb[(size_t)(sn + ks_s + 32) * 64 + ks_c];
            vr0 = *(const bf16x8*)&Vtb[(size_t)vd * 2112 + sn + vs];
            vr1 = *(const bf16x8*)&Vtb[(size_t)(vd + 32) * 2112 + sn + vs];
        }

        // ---- S^T tiles ----
        f32x16 sc[2];
#pragma unroll
        for (int ts = 0; ts < 2; ++ts) {
            f32x16 s16;
#pragma unroll
            for (int r = 0; r < 16; ++r) s16[r] = 0.f;
#pragma unroll
            for (int kt = 0; kt < 4; ++kt) {
                bf16x8 kf = *(const bf16x8*)&Ks[(ts * 32 + ln) * 72 + kt * 16 + hh * 8];
                s16 = MFMA32(kf, qf[kt], s16);
            }
            sc[ts] = s16;
        }

        // ---- exp2 + P write ----
        float rs = 0.f;
        if (s0 + 64 <= nkeys) {            // full chunk: all keys valid
#pragma unroll
            for (int ts = 0; ts < 2; ++ts)
#pragma unroll
                for (int rg = 0; rg < 4; ++rg) {
                    bf16x4 pb;
#pragma unroll
                    for (int i = 0; i < 4; ++i) {
                        float p = __builtin_amdgcn_exp2f(sc[ts][rg * 4 + i] - LOGBIAS);
                        rs += p;
                        pb[i] = (bf16)p;
                    }
                    *(bf16x4*)&Ps[wave][ln * 72 + ts * 32 + rg * 8 + hh * 4] = pb;
                }
        } else {                           // partial tail chunk
#pragma unroll
            for (int ts = 0; ts < 2; ++ts)
#pragma unroll
                for (int rg = 0; rg < 4; ++rg) {
                    bf16x4 pb;
#pragma unroll
                    for (int i = 0; i < 4; ++i) {
                        int key = s0 + ts * 32 + rg * 8 + hh * 4 + i;
                        float add = (key < nkeys) ? -LOGBIAS : -1e30f;
                        float p = __builtin_amdgcn_exp2f(sc[ts][rg * 4 + i] + add);
                        rs += p;
                        pb[i] = (bf16)p;
                    }
                    *(bf16x4*)&Ps[wave][ln * 72 + ts * 32 + rg * 8 + hh * 4] = pb;
                }
        }
        l_r += rs;

        __builtin_amdgcn_s_waitcnt(0xC07F);   // lgkmcnt(0): own Ps writes visible

        // ---- O^T += V^T * P ----
        bf16x8 pf[4];
#pragma unroll
        for (int ss = 0; ss < 4; ++ss)
            pf[ss] = *(const bf16x8*)&Ps[wave][ln * 72 + ss * 16 + hh * 8];
#pragma unroll
        for (int ss = 0; ss < 4; ++ss) {
            bf16x8 v0 = *(const bf16x8*)&Vt[ln * 72 + ss * 16 + hh * 8];
            acc[0] = MFMA32(v0, pf[ss], acc[0]);
            bf16x8 v1 = *(const bf16x8*)&Vt[(32 + ln) * 72 + ss * 16 + hh * 8];
            acc[1] = MFMA32(v1, pf[ss], acc[1]);
        }
    }

    // ---- epilogue ----
    l_r += __shfl_xor(l_r, 32);
    float inv = 1.0f / l_r;
#pragma unroll
    for (int td = 0; td < 2; ++td)
#pragma unroll
        for (int rg = 0; rg < 4; ++rg) {
            bf16x4 ob;
#pragma unroll
            for (int i = 0; i < 4; ++i) ob[i] = (bf16)(acc[td][rg * 4 + i] * inv);
            *(bf16x4*)&Ps[wave][ln * 72 + td * 32 + rg * 8 + hh * 4] = ob;
        }
    __builtin_amdgcn_s_waitcnt(0xC07F);
    const int orow = lane >> 3, oc = (lane & 7) * 8;
#pragma unroll
    for (int pass = 0; pass < 4; ++pass) {
        int ml = pass * 8 + orow;
        bf16x8 ov = *(const bf16x8*)&Ps[wave][ml * 72 + oc];
        int qrow = blockIdx.x * 128 + wave * 32 + ml;
        *(bf16x8*)&O[((size_t)b * 2048 + qrow) * 1024 + head * 64 + oc] = ov;
    }
}

// ---------------------------------------------------------------------------
// Output projection: out[m,n] = sum_k A[m,k]*Wo[n,k] + bo[n]; bf16 in, f32 out
// ---------------------------------------------------------------------------
__global__ __launch_bounds__(256) void out_proj_gemm(
    const bf16* __restrict__ A, const bf16* __restrict__ W,
    const float* __restrict__ bias, float* __restrict__ out)
{
    __shared__ bf16 As[128 * 32];
    __shared__ bf16 Bs[128 * 32];
    const int m0 = blockIdx.x * 128, n0 = blockIdx.y * 128;
    const int tid = threadIdx.x, lane = tid & 63, wave = tid >> 6;
    const int ln = lane & 15, quad = lane >> 4;
    const int wr = (wave >> 1) * 64, wc = (wave & 1) * 64;
    const int srow = wave * 32 + (lane >> 2);
    const int scol = (lane & 3) * 8;

    const f32x4 z4 = {0.f, 0.f, 0.f, 0.f};
    f32x4 acc[4][4];
#pragma unroll
    for (int i = 0; i < 4; ++i)
#pragma unroll
        for (int j = 0; j < 4; ++j) acc[i][j] = z4;

    for (int k0 = 0; k0 < 1024; k0 += 32) {
        __syncthreads();
        gl_lds16(&A[(size_t)(m0 + srow) * 1024 + k0 + scol],      &As[(wave * 32) * 32]);
        gl_lds16(&A[(size_t)(m0 + srow + 16) * 1024 + k0 + scol], &As[(wave * 32 + 16) * 32]);
        gl_lds16(&W[(size_t)(n0 + srow) * 1024 + k0 + scol],      &Bs[(wave * 32) * 32]);
        gl_lds16(&W[(size_t)(n0 + srow + 16) * 1024 + k0 + scol], &Bs[(wave * 32 + 16) * 32]);
        __syncthreads();
        bf16x8 af[4], bfr[4];
#pragma unroll
        for (int i = 0; i < 4; ++i) af[i]  = *(const bf16x8*)&As[(wr + i * 16 + ln) * 32 + quad * 8];
#pragma unroll
        for (int j = 0; j < 4; ++j) bfr[j] = *(const bf16x8*)&Bs[(wc + j * 16 + ln) * 32 + quad * 8];
#pragma unroll
        for (int i = 0; i < 4; ++i)
#pragma unroll
            for (int j = 0; j < 4; ++j)
                acc[i][j] = MFMA16(af[i], bfr[j], acc[i][j]);
    }

#pragma unroll
    for (int j = 0; j < 4; ++j) {
        const int n = n0 + wc + j * 16 + ln;
        const float bb = bias[n];
#pragma unroll
        for (int i = 0; i < 4; ++i) {
#pragma unroll
            for (int r = 0; r < 4; ++r) {
                int m = m0 + wr + i * 16 + quad * 4 + r;
                out[(size_t)m * 1024 + n] = acc[i][j][r] + bb;
            }
        }
    }
}

// ---------------------------------------------------------------------------
extern "C" void kernel_launch(void* const* d_in, const int* in_sizes, int n_in,
                              void* d_out, int out_size, void* d_ws, size_t ws_size,
                              hipStream_t stream)
{
    const float* x    = (const float*)d_in[0];
    const int*   mask = (const int*)d_in[1];
    const float* pk   = (const float*)d_in[2];
    const float* pv   = (const float*)d_in[3];
    const float* Wq   = (const float*)d_in[4];
    const float* bq   = (const float*)d_in[5];
    const float* Wk   = (const float*)d_in[6];
    const float* bk   = (const float*)d_in[7];
    const float* Wv   = (const float*)d_in[8];
    const float* bv   = (const float*)d_in[9];
    const float* Wo   = (const float*)d_in[10];
    const float* bo   = (const float*)d_in[11];
    float* out = (float*)d_out;

    bf16* xb    = (bf16*)d_ws;                   // [8192,1024] bf16
    bf16* wb    = xb + (size_t)8388608;          // 4 x [1024,1024] bf16
    bf16* q_ws  = wb + (size_t)4194304;          // [B,H,T,D]
    bf16* k_ws  = q_ws + (size_t)8388608;        // [B,H,S,D] compacted
    bf16* vt_ws = k_ws + (size_t)8650752;        // [B,H,D,S] compacted V^T
    int*  slot  = (int*)(vt_ws + (size_t)8650752);  // [B,T]
    int*  nkv   = slot + 4 * 2048;                  // [B]
    bf16* a_ws  = xb;   // alias: xb consumed by proj_qkv before attn writes

    cvt_all<<<dim3(12288), 256, 0, stream>>>(x, Wq, Wk, Wv, Wo, xb, wb);
    mask_scan<<<dim3(4), 256, 0, stream>>>(mask, slot, nkv);
    prefix_cvt<<<dim3(256), 256, 0, stream>>>(pk, pv, k_ws, vt_ws);
    proj_qkv_gemm<<<dim3(64, 8, 3), 256, 0, stream>>>(xb, wb, bq, bk, bv, slot,
                                                      q_ws, k_ws, vt_ws);
    attn_kernel<<<dim3(16, 64), 256, 0, stream>>>(q_ws, k_ws, vt_ws, nkv, a_ws);
    out_proj_gemm<<<dim3(64, 8), 256, 0, stream>>>(a_ws, wb + (size_t)3 * 1048576,
                                                   bo, out);
}

// Round 5
// 275.309 us; speedup vs baseline: 1.8850x; 1.0291x over previous
//
#include <hip/hip_runtime.h>
#include <hip/hip_bf16.h>

typedef __bf16 bf16;
typedef __attribute__((ext_vector_type(8))) __bf16 bf16x8;
typedef __attribute__((ext_vector_type(4))) __bf16 bf16x4;
typedef __attribute__((ext_vector_type(4))) float f32x4;
typedef __attribute__((ext_vector_type(16))) float f32x16;

#define MFMA16(a, b, c) __builtin_amdgcn_mfma_f32_16x16x32_bf16(a, b, c, 0, 0, 0)
#define MFMA32(a, b, c) __builtin_amdgcn_mfma_f32_32x32x16_bf16(a, b, c, 0, 0, 0)

__device__ __forceinline__ void gl_lds16(const void* g, void* l) {
    __builtin_amdgcn_global_load_lds(
        (const __attribute__((address_space(1))) void*)g,
        (__attribute__((address_space(3))) void*)l, 16, 0, 0);
}

// Problem constants: B=4, T=2048, C=1024, H=16, D=64, P=64, S=2112
// Q scale folds 1/sqrt(D)*log2(e); softmax uses fixed bias -24 (scores are
// N(0,~1.44) in log2 domain; the bias cancels in normalization exactly).
#define QSCALE 0.18033688011f
#define LOGBIAS 24.0f

// ---------------------------------------------------------------------------
// prep: one dispatch doing (a) per-batch mask scan -> ridx/nk, (b) prefix K/V
// cvt into compacted K / V^T slots [0,64), (c) fp32->bf16 precast of x and W.
// Block ranges: [0,4) scan, [4,260) prefix, [260,12548) cvt.
// ---------------------------------------------------------------------------
__global__ __launch_bounds__(256) void prep(
    const float* __restrict__ x, const float* __restrict__ Wq,
    const float* __restrict__ Wk, const float* __restrict__ Wv,
    const float* __restrict__ Wo, const float* __restrict__ pk,
    const float* __restrict__ pv, const int* __restrict__ mask,
    bf16* __restrict__ xb, bf16* __restrict__ wb,
    bf16* __restrict__ k_ws, bf16* __restrict__ vt_ws,
    int* __restrict__ ridx, int* __restrict__ nkv)
{
    const int blk = blockIdx.x, tid = threadIdx.x;
    if (blk < 4) {
        // ---- per-batch mask scan: ridx[b][i] = t of i-th visible key ----
        const int b = blk, lane = tid & 63, wv = tid >> 6;
        const int* mb = mask + b * 2048;
        int loc[8], s = 0;
#pragma unroll
        for (int e = 0; e < 8; ++e) { loc[e] = (mb[tid * 8 + e] != 0); s += loc[e]; }
        int inc = s;
#pragma unroll
        for (int off = 1; off < 64; off <<= 1) {
            int t = __shfl_up(inc, off);
            if (lane >= off) inc += t;
        }
        __shared__ int wt[4];
        if (lane == 63) wt[wv] = inc;
        __syncthreads();
        int wo = 0;
        for (int w = 0; w < wv; ++w) wo += wt[w];
        int excl = wo + inc - s;
#pragma unroll
        for (int e = 0; e < 8; ++e) {
            if (loc[e]) ridx[b * 2048 + excl] = tid * 8 + e;
            excl += loc[e];
        }
        if (tid == 255) nkv[b] = 64 + wo + inc;
    } else if (blk < 260) {
        // ---- prefix K -> k_ws slots [0,64); prefix V -> vt_ws transposed ----
        int i = (blk - 4) * 256 + tid;          // 0..65535
        {
            int base = i * 4;
            int bh = base >> 12, rem = base & 4095;
            float4 a = *(const float4*)&pk[base];
            bf16x4 ab;
            ab[0] = (bf16)a.x; ab[1] = (bf16)a.y; ab[2] = (bf16)a.z; ab[3] = (bf16)a.w;
            *(bf16x4*)&k_ws[(size_t)bh * (2112 * 64) + rem] = ab;
        }
        {
            int bh = i >> 10, r = i & 1023;
            int d = r >> 4, sq = (r & 15) * 4;
            bf16x4 vb;
#pragma unroll
            for (int e = 0; e < 4; ++e)
                vb[e] = (bf16)pv[(size_t)bh * 4096 + (sq + e) * 64 + d];
            *(bf16x4*)&vt_ws[((size_t)bh * 64 + d) * 2112 + sq] = vb;
        }
    } else {
        // ---- fp32 -> bf16 precast ----
        int i4 = (blk - 260) * 256 + tid;       // 0..3145727
        const float* src; bf16* dst; int off;
        if (i4 < 2097152) { src = x; dst = xb; off = i4; }
        else {
            int j = i4 - 2097152;
            int sel = j >> 18;
            off = j & 262143;
            src = (sel == 0) ? Wq : (sel == 1) ? Wk : (sel == 2) ? Wv : Wo;
            dst = wb + (size_t)sel * 1048576;
        }
        float4 a = *(const float4*)&src[(size_t)off * 4];
        bf16x4 o;
        o[0] = (bf16)a.x; o[1] = (bf16)a.y; o[2] = (bf16)a.z; o[3] = (bf16)a.w;
        *(bf16x4*)&dst[(size_t)off * 4] = o;
    }
}

// ---------------------------------------------------------------------------
// Q projection (full M=8192).  Epilogue -> q_ws [B,H,T,D], QSCALE folded.
// ---------------------------------------------------------------------------
__global__ __launch_bounds__(256) void proj_q_gemm(
    const bf16* __restrict__ X, const bf16* __restrict__ W,
    const float* __restrict__ bias, bf16* __restrict__ q_ws)
{
    __shared__ bf16 As[128 * 32];
    __shared__ bf16 Bs[128 * 32];
    const int m0 = blockIdx.x * 128, n0 = blockIdx.y * 128;
    const int tid = threadIdx.x, lane = tid & 63, wave = tid >> 6;
    const int ln = lane & 15, quad = lane >> 4;
    const int wr = (wave >> 1) * 64, wc = (wave & 1) * 64;
    const int srow = wave * 32 + (lane >> 2);
    const int scol = (lane & 3) * 8;

    const f32x4 z4 = {0.f, 0.f, 0.f, 0.f};
    f32x4 acc[4][4];
#pragma unroll
    for (int i = 0; i < 4; ++i)
#pragma unroll
        for (int j = 0; j < 4; ++j) acc[i][j] = z4;

    for (int k0 = 0; k0 < 1024; k0 += 32) {
        __syncthreads();
        gl_lds16(&X[(size_t)(m0 + srow) * 1024 + k0 + scol],      &As[(wave * 32) * 32]);
        gl_lds16(&X[(size_t)(m0 + srow + 16) * 1024 + k0 + scol], &As[(wave * 32 + 16) * 32]);
        gl_lds16(&W[(size_t)(n0 + srow) * 1024 + k0 + scol],      &Bs[(wave * 32) * 32]);
        gl_lds16(&W[(size_t)(n0 + srow + 16) * 1024 + k0 + scol], &Bs[(wave * 32 + 16) * 32]);
        __syncthreads();
        bf16x8 af[4], bfr[4];
#pragma unroll
        for (int i = 0; i < 4; ++i) af[i]  = *(const bf16x8*)&As[(wr + i * 16 + ln) * 32 + quad * 8];
#pragma unroll
        for (int j = 0; j < 4; ++j) bfr[j] = *(const bf16x8*)&Bs[(wc + j * 16 + ln) * 32 + quad * 8];
#pragma unroll
        for (int i = 0; i < 4; ++i)
#pragma unroll
            for (int j = 0; j < 4; ++j)
                acc[i][j] = MFMA16(af[i], bfr[j], acc[i][j]);
    }

#pragma unroll
    for (int j = 0; j < 4; ++j) {
        const int n = n0 + wc + j * 16 + ln;
        const float bb = bias[n];
        const int h = n >> 6, d = n & 63;
#pragma unroll
        for (int i = 0; i < 4; ++i) {
            int m = m0 + wr + i * 16 + quad * 4;
            int b = m >> 11, t = m & 2047;
#pragma unroll
            for (int r = 0; r < 4; ++r)
                q_ws[((size_t)(b * 16 + h) * 2048 + t + r) * 64 + d] =
                    (bf16)((acc[i][j][r] + bb) * QSCALE);
        }
    }
}

// ---------------------------------------------------------------------------
// K/V projection over COMPACTED visible rows (gathered A-stage via ridx).
// blockIdx.x = b*16 + tile (tiles past nvis exit); z = 0(K)/1(V).
// Compacted row i is key slot 64+i: K stores sequential, V^T packed 8B.
// ---------------------------------------------------------------------------
__global__ __launch_bounds__(256) void proj_kv_gemm(
    const bf16* __restrict__ X, const bf16* __restrict__ Wb,
    const float* __restrict__ bk, const float* __restrict__ bv,
    const int* __restrict__ ridx, const int* __restrict__ nkv,
    bf16* __restrict__ k_ws, bf16* __restrict__ vt_ws)
{
    const int bsel = blockIdx.x >> 4, tile = blockIdx.x & 15;
    const int nvis = nkv[bsel] - 64;
    const int mbase = tile * 128;
    if (mbase >= nvis) return;

    __shared__ bf16 As[128 * 32];
    __shared__ bf16 Bs[128 * 32];
    const int mode = blockIdx.z;               // 0 = K, 1 = V
    const bf16* __restrict__ W = Wb + (size_t)(1 + mode) * 1048576;
    const float* __restrict__ bias = mode ? bv : bk;
    const int n0 = blockIdx.y * 128;
    const int tid = threadIdx.x, lane = tid & 63, wave = tid >> 6;
    const int ln = lane & 15, quad = lane >> 4;
    const int wr = (wave >> 1) * 64, wc = (wave & 1) * 64;
    const int srow = wave * 32 + (lane >> 2);
    const int scol = (lane & 3) * 8;

    // gathered A-row addresses (k-invariant)
    int g0 = mbase + srow,      g1 = g0 + 16;
    int c0 = (g0 < nvis) ? g0 : nvis - 1;
    int c1 = (g1 < nvis) ? g1 : nvis - 1;
    const bf16* Xr0 = X + (size_t)(bsel * 2048 + ridx[bsel * 2048 + c0]) * 1024 + scol;
    const bf16* Xr1 = X + (size_t)(bsel * 2048 + ridx[bsel * 2048 + c1]) * 1024 + scol;

    const f32x4 z4 = {0.f, 0.f, 0.f, 0.f};
    f32x4 acc[4][4];
#pragma unroll
    for (int i = 0; i < 4; ++i)
#pragma unroll
        for (int j = 0; j < 4; ++j) acc[i][j] = z4;

    for (int k0 = 0; k0 < 1024; k0 += 32) {
        __syncthreads();
        gl_lds16(Xr0 + k0, &As[(wave * 32) * 32]);
        gl_lds16(Xr1 + k0, &As[(wave * 32 + 16) * 32]);
        gl_lds16(&W[(size_t)(n0 + srow) * 1024 + k0 + scol],      &Bs[(wave * 32) * 32]);
        gl_lds16(&W[(size_t)(n0 + srow + 16) * 1024 + k0 + scol], &Bs[(wave * 32 + 16) * 32]);
        __syncthreads();
        bf16x8 af[4], bfr[4];
#pragma unroll
        for (int i = 0; i < 4; ++i) af[i]  = *(const bf16x8*)&As[(wr + i * 16 + ln) * 32 + quad * 8];
#pragma unroll
        for (int j = 0; j < 4; ++j) bfr[j] = *(const bf16x8*)&Bs[(wc + j * 16 + ln) * 32 + quad * 8];
#pragma unroll
        for (int i = 0; i < 4; ++i)
#pragma unroll
            for (int j = 0; j < 4; ++j)
                acc[i][j] = MFMA16(af[i], bfr[j], acc[i][j]);
    }

#pragma unroll
    for (int j = 0; j < 4; ++j) {
        const int n = n0 + wc + j * 16 + ln;
        const float bb = bias[n];
        const int h = n >> 6, d = n & 63;
        const size_t bh64 = (size_t)(bsel * 16 + h);
#pragma unroll
        for (int i = 0; i < 4; ++i) {
            int ml = mbase + wr + i * 16 + quad * 4;   // compacted row of first r
            if (mode == 0) {
#pragma unroll
                for (int r = 0; r < 4; ++r)
                    if (ml + r < nvis)
                        k_ws[(bh64 * 2112 + 64 + ml + r) * 64 + d] =
                            (bf16)(acc[i][j][r] + bb);
            } else {
                if (ml + 3 < nvis) {
                    bf16x4 pb;
#pragma unroll
                    for (int r = 0; r < 4; ++r) pb[r] = (bf16)(acc[i][j][r] + bb);
                    *(bf16x4*)&vt_ws[(bh64 * 64 + d) * 2112 + 64 + ml] = pb;
                } else {
#pragma unroll
                    for (int r = 0; r < 4; ++r)
                        if (ml + r < nvis)
                            vt_ws[(bh64 * 64 + d) * 2112 + 64 + ml + r] =
                                (bf16)(acc[i][j][r] + bb);
                }
            }
        }
    }
}

// ---------------------------------------------------------------------------
// Flash attention over COMPACTED keys (nkeys = 64 + nvis per batch).
// 32x32x16 MFMA, S^T form, fixed-bias softmax.  Block = 4 waves x 32 queries.
// Slots >= nkeys get -1e30 (poisoned K is finite; exp2 -> exact 0).
// ---------------------------------------------------------------------------
__global__ __launch_bounds__(256) void attn_kernel(
    const bf16* __restrict__ Q, const bf16* __restrict__ K,
    const bf16* __restrict__ VT, const int* __restrict__ nk,
    bf16* __restrict__ O)
{
    __shared__ bf16 Ks[64 * 72];
    __shared__ bf16 Vt[64 * 72];
    __shared__ bf16 Ps[4][32 * 72];
    const int tid = threadIdx.x, wave = tid >> 6, lane = tid & 63;
    const int ln = lane & 31, hh = lane >> 5;
    const int bh = blockIdx.y, b = bh >> 4, head = bh & 15;
    const bf16* __restrict__ Kb  = K  + (size_t)bh * (2112 * 64);
    const bf16* __restrict__ Vtb = VT + (size_t)bh * (64 * 2112);
    const int qg = blockIdx.x * 128 + wave * 32 + ln;
    const int nkeys = nk[b];
    const int send = ((nkeys + 63) >> 6) << 6;

    bf16x8 qf[4];
#pragma unroll
    for (int kt = 0; kt < 4; ++kt)
        qf[kt] = *(const bf16x8*)&Q[((size_t)bh * 2048 + qg) * 64 + kt * 16 + hh * 8];

    float l_r = 0.f;
    f32x16 acc[2];
#pragma unroll
    for (int r = 0; r < 16; ++r) { acc[0][r] = 0.f; acc[1][r] = 0.f; }

    const int ks_s = tid >> 3, ks_c = (tid & 7) * 8;
    const int vd = tid >> 3,  vs = (tid & 7) * 8;

    bf16x8 kr0, kr1, vr0, vr1;
    kr0 = *(const bf16x8*)&Kb[(size_t)ks_s * 64 + ks_c];
    kr1 = *(const bf16x8*)&Kb[(size_t)(ks_s + 32) * 64 + ks_c];
    vr0 = *(const bf16x8*)&Vtb[(size_t)vd * 2112 + vs];
    vr1 = *(const bf16x8*)&Vtb[(size_t)(vd + 32) * 2112 + vs];

    for (int s0 = 0; s0 < send; s0 += 64) {
        __syncthreads();
        *(bf16x8*)&Ks[ks_s * 72 + ks_c]        = kr0;
        *(bf16x8*)&Ks[(ks_s + 32) * 72 + ks_c] = kr1;
        *(bf16x8*)&Vt[vd * 72 + vs]            = vr0;
        *(bf16x8*)&Vt[(vd + 32) * 72 + vs]     = vr1;
        __syncthreads();

        if (s0 + 64 < send) {
            const int sn = s0 + 64;
            kr0 = *(const bf16x8*)&Kb[(size_t)(sn + ks_s) * 64 + ks_c];
            kr1 = *(const bf16x8*)&Kb[(size_t)(sn + ks_s + 32) * 64 + ks_c];
            vr0 = *(const bf16x8*)&Vtb[(size_t)vd * 2112 + sn + vs];
            vr1 = *(const bf16x8*)&Vtb[(size_t)(vd + 32) * 2112 + sn + vs];
        }

        f32x16 sc[2];
#pragma unroll
        for (int ts = 0; ts < 2; ++ts) {
            f32x16 s16;
#pragma unroll
            for (int r = 0; r < 16; ++r) s16[r] = 0.f;
#pragma unroll
            for (int kt = 0; kt < 4; ++kt) {
                bf16x8 kf = *(const bf16x8*)&Ks[(ts * 32 + ln) * 72 + kt * 16 + hh * 8];
                s16 = MFMA32(kf, qf[kt], s16);
            }
            sc[ts] = s16;
        }

        float rs = 0.f;
        if (s0 + 64 <= nkeys) {
#pragma unroll
            for (int ts = 0; ts < 2; ++ts)
#pragma unroll
                for (int rg = 0; rg < 4; ++rg) {
                    bf16x4 pb;
#pragma unroll
                    for (int i = 0; i < 4; ++i) {
                        float p = __builtin_amdgcn_exp2f(sc[ts][rg * 4 + i] - LOGBIAS);
                        rs += p;
                        pb[i] = (bf16)p;
                    }
                    *(bf16x4*)&Ps[wave][ln * 72 + ts * 32 + rg * 8 + hh * 4] = pb;
                }
        } else {
#pragma unroll
            for (int ts = 0; ts < 2; ++ts)
#pragma unroll
                for (int rg = 0; rg < 4; ++rg) {
                    bf16x4 pb;
#pragma unroll
                    for (int i = 0; i < 4; ++i) {
                        int key = s0 + ts * 32 + rg * 8 + hh * 4 + i;
                        float add = (key < nkeys) ? -LOGBIAS : -1e30f;
                        float p = __builtin_amdgcn_exp2f(sc[ts][rg * 4 + i] + add);
                        rs += p;
                        pb[i] = (bf16)p;
                    }
                    *(bf16x4*)&Ps[wave][ln * 72 + ts * 32 + rg * 8 + hh * 4] = pb;
                }
        }
        l_r += rs;

        __builtin_amdgcn_s_waitcnt(0xC07F);   // lgkmcnt(0): own Ps writes visible

        bf16x8 pf[4];
#pragma unroll
        for (int ss = 0; ss < 4; ++ss)
            pf[ss] = *(const bf16x8*)&Ps[wave][ln * 72 + ss * 16 + hh * 8];
#pragma unroll
        for (int ss = 0; ss < 4; ++ss) {
            bf16x8 v0 = *(const bf16x8*)&Vt[ln * 72 + ss * 16 + hh * 8];
            acc[0] = MFMA32(v0, pf[ss], acc[0]);
            bf16x8 v1 = *(const bf16x8*)&Vt[(32 + ln) * 72 + ss * 16 + hh * 8];
            acc[1] = MFMA32(v1, pf[ss], acc[1]);
        }
    }

    l_r += __shfl_xor(l_r, 32);
    float inv = 1.0f / l_r;
#pragma unroll
    for (int td = 0; td < 2; ++td)
#pragma unroll
        for (int rg = 0; rg < 4; ++rg) {
            bf16x4 ob;
#pragma unroll
            for (int i = 0; i < 4; ++i) ob[i] = (bf16)(acc[td][rg * 4 + i] * inv);
            *(bf16x4*)&Ps[wave][ln * 72 + td * 32 + rg * 8 + hh * 4] = ob;
        }
    __builtin_amdgcn_s_waitcnt(0xC07F);
    const int orow = lane >> 3, oc = (lane & 7) * 8;
#pragma unroll
    for (int pass = 0; pass < 4; ++pass) {
        int ml = pass * 8 + orow;
        bf16x8 ov = *(const bf16x8*)&Ps[wave][ml * 72 + oc];
        int qrow = blockIdx.x * 128 + wave * 32 + ml;
        *(bf16x8*)&O[((size_t)b * 2048 + qrow) * 1024 + head * 64 + oc] = ov;
    }
}

// ---------------------------------------------------------------------------
// Output projection: out[m,n] = sum_k A[m,k]*Wo[n,k] + bo[n]; bf16 in, f32 out
// ---------------------------------------------------------------------------
__global__ __launch_bounds__(256) void out_proj_gemm(
    const bf16* __restrict__ A, const bf16* __restrict__ W,
    const float* __restrict__ bias, float* __restrict__ out)
{
    __shared__ bf16 As[128 * 32];
    __shared__ bf16 Bs[128 * 32];
    const int m0 = blockIdx.x * 128, n0 = blockIdx.y * 128;
    const int tid = threadIdx.x, lane = tid & 63, wave = tid >> 6;
    const int ln = lane & 15, quad = lane >> 4;
    const int wr = (wave >> 1) * 64, wc = (wave & 1) * 64;
    const int srow = wave * 32 + (lane >> 2);
    const int scol = (lane & 3) * 8;

    const f32x4 z4 = {0.f, 0.f, 0.f, 0.f};
    f32x4 acc[4][4];
#pragma unroll
    for (int i = 0; i < 4; ++i)
#pragma unroll
        for (int j = 0; j < 4; ++j) acc[i][j] = z4;

    for (int k0 = 0; k0 < 1024; k0 += 32) {
        __syncthreads();
        gl_lds16(&A[(size_t)(m0 + srow) * 1024 + k0 + scol],      &As[(wave * 32) * 32]);
        gl_lds16(&A[(size_t)(m0 + srow + 16) * 1024 + k0 + scol], &As[(wave * 32 + 16) * 32]);
        gl_lds16(&W[(size_t)(n0 + srow) * 1024 + k0 + scol],      &Bs[(wave * 32) * 32]);
        gl_lds16(&W[(size_t)(n0 + srow + 16) * 1024 + k0 + scol], &Bs[(wave * 32 + 16) * 32]);
        __syncthreads();
        bf16x8 af[4], bfr[4];
#pragma unroll
        for (int i = 0; i < 4; ++i) af[i]  = *(const bf16x8*)&As[(wr + i * 16 + ln) * 32 + quad * 8];
#pragma unroll
        for (int j = 0; j < 4; ++j) bfr[j] = *(const bf16x8*)&Bs[(wc + j * 16 + ln) * 32 + quad * 8];
#pragma unroll
        for (int i = 0; i < 4; ++i)
#pragma unroll
            for (int j = 0; j < 4; ++j)
                acc[i][j] = MFMA16(af[i], bfr[j], acc[i][j]);
    }

#pragma unroll
    for (int j = 0; j < 4; ++j) {
        const int n = n0 + wc + j * 16 + ln;
        const float bb = bias[n];
#pragma unroll
        for (int i = 0; i < 4; ++i) {
#pragma unroll
            for (int r = 0; r < 4; ++r) {
                int m = m0 + wr + i * 16 + quad * 4 + r;
                out[(size_t)m * 1024 + n] = acc[i][j][r] + bb;
            }
        }
    }
}

// ---------------------------------------------------------------------------
extern "C" void kernel_launch(void* const* d_in, const int* in_sizes, int n_in,
                              void* d_out, int out_size, void* d_ws, size_t ws_size,
                              hipStream_t stream)
{
    const float* x    = (const float*)d_in[0];
    const int*   mask = (const int*)d_in[1];
    const float* pk   = (const float*)d_in[2];
    const float* pv   = (const float*)d_in[3];
    const float* Wq   = (const float*)d_in[4];
    const float* bq   = (const float*)d_in[5];
    const float* Wk   = (const float*)d_in[6];
    const float* bk   = (const float*)d_in[7];
    const float* Wv   = (const float*)d_in[8];
    const float* bv   = (const float*)d_in[9];
    const float* Wo   = (const float*)d_in[10];
    const float* bo   = (const float*)d_in[11];
    float* out = (float*)d_out;

    bf16* xb    = (bf16*)d_ws;                   // [8192,1024] bf16
    bf16* wb    = xb + (size_t)8388608;          // 4 x [1024,1024] bf16
    bf16* q_ws  = wb + (size_t)4194304;          // [B,H,T,D]
    bf16* k_ws  = q_ws + (size_t)8388608;        // [B,H,S,D] compacted
    bf16* vt_ws = k_ws + (size_t)8650752;        // [B,H,D,S] compacted V^T
    int*  ridx  = (int*)(vt_ws + (size_t)8650752);  // [B,T] visible-row gather
    int*  nkv   = ridx + 4 * 2048;                  // [B]
    bf16* a_ws  = xb;   // alias: xb consumed by projections before attn writes

    prep<<<dim3(12548), 256, 0, stream>>>(x, Wq, Wk, Wv, Wo, pk, pv, mask,
                                          xb, wb, k_ws, vt_ws, ridx, nkv);
    proj_q_gemm<<<dim3(64, 8), 256, 0, stream>>>(xb, wb, bq, q_ws);
    proj_kv_gemm<<<dim3(64, 8, 2), 256, 0, stream>>>(xb, wb, bk, bv, ridx, nkv,
                                                     k_ws, vt_ws);
    attn_kernel<<<dim3(16, 64), 256, 0, stream>>>(q_ws, k_ws, vt_ws, nkv, a_ws);
    out_proj_gemm<<<dim3(64, 8), 256, 0, stream>>>(a_ws, wb + (size_t)3 * 1048576,
                                                   bo, out);
}

// Round 6
// 256.511 us; speedup vs baseline: 2.0232x; 1.0733x over previous
//
#include <hip/hip_runtime.h>
#include <hip/hip_bf16.h>

typedef __bf16 bf16;
typedef __attribute__((ext_vector_type(8))) __bf16 bf16x8;
typedef __attribute__((ext_vector_type(4))) __bf16 bf16x4;
typedef __attribute__((ext_vector_type(4))) float f32x4;
typedef __attribute__((ext_vector_type(16))) float f32x16;

#define MFMA16(a, b, c) __builtin_amdgcn_mfma_f32_16x16x32_bf16(a, b, c, 0, 0, 0)
#define MFMA32(a, b, c) __builtin_amdgcn_mfma_f32_32x32x16_bf16(a, b, c, 0, 0, 0)

__device__ __forceinline__ void gl_lds16(const void* g, void* l) {
    __builtin_amdgcn_global_load_lds(
        (const __attribute__((address_space(1))) void*)g,
        (__attribute__((address_space(3))) void*)l, 16, 0, 0);
}

// Problem constants: B=4, T=2048, C=1024, H=16, D=64, P=64, S=2112
// Q scale folds 1/sqrt(D)*log2(e); softmax uses fixed bias -24 (scores are
// N(0,~1.44) in log2 domain; the bias cancels in normalization exactly).
#define QSCALE 0.18033688011f
#define LOGBIAS 24.0f

// ---------------------------------------------------------------------------
// prep: (a) per-batch mask scan -> ridx/nk, (b) prefix K/V cvt into slots
// [0,64) (V^T in PERMUTED column order is NOT needed here: permutation only
// applies inside attn LDS staging), (c) fp32->bf16 precast of x and W.
// ---------------------------------------------------------------------------
__global__ __launch_bounds__(256) void prep(
    const float* __restrict__ x, const float* __restrict__ Wq,
    const float* __restrict__ Wk, const float* __restrict__ Wv,
    const float* __restrict__ Wo, const float* __restrict__ pk,
    const float* __restrict__ pv, const int* __restrict__ mask,
    bf16* __restrict__ xb, bf16* __restrict__ wb,
    bf16* __restrict__ k_ws, bf16* __restrict__ vt_ws,
    int* __restrict__ ridx, int* __restrict__ nkv)
{
    const int blk = blockIdx.x, tid = threadIdx.x;
    if (blk < 4) {
        const int b = blk, lane = tid & 63, wv = tid >> 6;
        const int* mb = mask + b * 2048;
        int loc[8], s = 0;
#pragma unroll
        for (int e = 0; e < 8; ++e) { loc[e] = (mb[tid * 8 + e] != 0); s += loc[e]; }
        int inc = s;
#pragma unroll
        for (int off = 1; off < 64; off <<= 1) {
            int t = __shfl_up(inc, off);
            if (lane >= off) inc += t;
        }
        __shared__ int wt[4];
        if (lane == 63) wt[wv] = inc;
        __syncthreads();
        int wo = 0;
        for (int w = 0; w < wv; ++w) wo += wt[w];
        int excl = wo + inc - s;
#pragma unroll
        for (int e = 0; e < 8; ++e) {
            if (loc[e]) ridx[b * 2048 + excl] = tid * 8 + e;
            excl += loc[e];
        }
        if (tid == 255) nkv[b] = 64 + wo + inc;
    } else if (blk < 260) {
        int i = (blk - 4) * 256 + tid;
        {
            int base = i * 4;
            int bh = base >> 12, rem = base & 4095;
            float4 a = *(const float4*)&pk[base];
            bf16x4 ab;
            ab[0] = (bf16)a.x; ab[1] = (bf16)a.y; ab[2] = (bf16)a.z; ab[3] = (bf16)a.w;
            *(bf16x4*)&k_ws[(size_t)bh * (2112 * 64) + rem] = ab;
        }
        {
            int bh = i >> 10, r = i & 1023;
            int d = r >> 4, sq = (r & 15) * 4;
            bf16x4 vb;
#pragma unroll
            for (int e = 0; e < 4; ++e)
                vb[e] = (bf16)pv[(size_t)bh * 4096 + (sq + e) * 64 + d];
            *(bf16x4*)&vt_ws[((size_t)bh * 64 + d) * 2112 + sq] = vb;
        }
    } else {
        int i4 = (blk - 260) * 256 + tid;
        const float* src; bf16* dst; int off;
        if (i4 < 2097152) { src = x; dst = xb; off = i4; }
        else {
            int j = i4 - 2097152;
            int sel = j >> 18;
            off = j & 262143;
            src = (sel == 0) ? Wq : (sel == 1) ? Wk : (sel == 2) ? Wv : Wo;
            dst = wb + (size_t)sel * 1048576;
        }
        float4 a = *(const float4*)&src[(size_t)off * 4];
        bf16x4 o;
        o[0] = (bf16)a.x; o[1] = (bf16)a.y; o[2] = (bf16)a.z; o[3] = (bf16)a.w;
        *(bf16x4*)&dst[(size_t)off * 4] = o;
    }
}

// ---------------------------------------------------------------------------
// Merged projection dispatch.  blocks [0,512): Q (full M); [512,1536): K/V
// over compacted rows (gathered A via ridx; dead tiles exit).
// ---------------------------------------------------------------------------
__global__ __launch_bounds__(256) void proj_gemm(
    const bf16* __restrict__ X, const bf16* __restrict__ Wb,
    const float* __restrict__ bq, const float* __restrict__ bk,
    const float* __restrict__ bv, const int* __restrict__ ridx,
    const int* __restrict__ nkv,
    bf16* __restrict__ q_ws, bf16* __restrict__ k_ws, bf16* __restrict__ vt_ws)
{
    const int bx = blockIdx.x;
    int kind, m0 = 0, n0, bsel = 0, nvis = 0, mbase = 0;
    const bf16* W;
    const float* bias;
    if (bx < 512) {
        kind = 0; m0 = (bx >> 3) * 128; n0 = (bx & 7) * 128;
        W = Wb; bias = bq;
    } else {
        int j = bx - 512;
        kind = 1 + (j >> 9);
        int r = j & 511;
        bsel = r >> 7;
        mbase = ((r & 127) >> 3) * 128;
        n0 = (r & 7) * 128;
        nvis = nkv[bsel] - 64;
        if (mbase >= nvis) return;
        W = Wb + (size_t)kind * 1048576;
        bias = (kind == 1) ? bk : bv;
    }

    __shared__ bf16 As[128 * 32];
    __shared__ bf16 Bs[128 * 32];
    const int tid = threadIdx.x, lane = tid & 63, wave = tid >> 6;
    const int ln = lane & 15, quad = lane >> 4;
    const int wr = (wave >> 1) * 64, wc = (wave & 1) * 64;
    const int srow = wave * 32 + (lane >> 2);
    const int scol = (lane & 3) * 8;

    const bf16 *Xr0, *Xr1;
    if (kind == 0) {
        Xr0 = X + (size_t)(m0 + srow) * 1024 + scol;
        Xr1 = Xr0 + (size_t)16 * 1024;
    } else {
        int g0 = mbase + srow, g1 = g0 + 16;
        int c0 = (g0 < nvis) ? g0 : nvis - 1;
        int c1 = (g1 < nvis) ? g1 : nvis - 1;
        Xr0 = X + (size_t)(bsel * 2048 + ridx[bsel * 2048 + c0]) * 1024 + scol;
        Xr1 = X + (size_t)(bsel * 2048 + ridx[bsel * 2048 + c1]) * 1024 + scol;
    }

    const f32x4 z4 = {0.f, 0.f, 0.f, 0.f};
    f32x4 acc[4][4];
#pragma unroll
    for (int i = 0; i < 4; ++i)
#pragma unroll
        for (int j = 0; j < 4; ++j) acc[i][j] = z4;

    for (int k0 = 0; k0 < 1024; k0 += 32) {
        __syncthreads();
        gl_lds16(Xr0 + k0, &As[(wave * 32) * 32]);
        gl_lds16(Xr1 + k0, &As[(wave * 32 + 16) * 32]);
        gl_lds16(&W[(size_t)(n0 + srow) * 1024 + k0 + scol],      &Bs[(wave * 32) * 32]);
        gl_lds16(&W[(size_t)(n0 + srow + 16) * 1024 + k0 + scol], &Bs[(wave * 32 + 16) * 32]);
        __syncthreads();
        bf16x8 af[4], bfr[4];
#pragma unroll
        for (int i = 0; i < 4; ++i) af[i]  = *(const bf16x8*)&As[(wr + i * 16 + ln) * 32 + quad * 8];
#pragma unroll
        for (int j = 0; j < 4; ++j) bfr[j] = *(const bf16x8*)&Bs[(wc + j * 16 + ln) * 32 + quad * 8];
#pragma unroll
        for (int i = 0; i < 4; ++i)
#pragma unroll
            for (int j = 0; j < 4; ++j)
                acc[i][j] = MFMA16(af[i], bfr[j], acc[i][j]);
    }

    if (kind == 0) {
#pragma unroll
        for (int j = 0; j < 4; ++j) {
            const int n = n0 + wc + j * 16 + ln;
            const float bb = bias[n];
            const int h = n >> 6, d = n & 63;
#pragma unroll
            for (int i = 0; i < 4; ++i) {
                int m = m0 + wr + i * 16 + quad * 4;
                int b = m >> 11, t = m & 2047;
#pragma unroll
                for (int r = 0; r < 4; ++r)
                    q_ws[((size_t)(b * 16 + h) * 2048 + t + r) * 64 + d] =
                        (bf16)((acc[i][j][r] + bb) * QSCALE);
            }
        }
    } else {
#pragma unroll
        for (int j = 0; j < 4; ++j) {
            const int n = n0 + wc + j * 16 + ln;
            const float bb = bias[n];
            const int h = n >> 6, d = n & 63;
            const size_t bh64 = (size_t)(bsel * 16 + h);
#pragma unroll
            for (int i = 0; i < 4; ++i) {
                int ml = mbase + wr + i * 16 + quad * 4;
                if (kind == 1) {
#pragma unroll
                    for (int r = 0; r < 4; ++r)
                        if (ml + r < nvis)
                            k_ws[(bh64 * 2112 + 64 + ml + r) * 64 + d] =
                                (bf16)(acc[i][j][r] + bb);
                } else {
                    if (ml + 3 < nvis) {
                        bf16x4 pb;
#pragma unroll
                        for (int r = 0; r < 4; ++r) pb[r] = (bf16)(acc[i][j][r] + bb);
                        *(bf16x4*)&vt_ws[(bh64 * 64 + d) * 2112 + 64 + ml] = pb;
                    } else {
#pragma unroll
                        for (int r = 0; r < 4; ++r)
                            if (ml + r < nvis)
                                vt_ws[(bh64 * 64 + d) * 2112 + 64 + ml + r] =
                                    (bf16)(acc[i][j][r] + bb);
                    }
                }
            }
        }
    }
}

// ---------------------------------------------------------------------------
// Flash attention v3: compacted keys, fixed-bias softmax, and REGISTER-ONLY
// P: PV's key dimension is permuted (sigma(hh*8+j) = lane's own C-reg order)
// so the PV B-fragment is the lane's own packed p regs.  The permutation is
// absorbed into Vt's LDS column order at staging (swap middle quads of each
// 16).  No Ps LDS, no lgkm round-trip; LDS = 18.4 KB.
// ---------------------------------------------------------------------------
__global__ __launch_bounds__(256) void attn_kernel(
    const bf16* __restrict__ Q, const bf16* __restrict__ K,
    const bf16* __restrict__ VT, const int* __restrict__ nk,
    bf16* __restrict__ O)
{
    __shared__ bf16 smem[128 * 72];
    bf16* Ks = smem;               // [s][d] rows 0..63, stride 72
    bf16* Vt = smem + 64 * 72;     // [d][s-permuted] rows 0..63, stride 72
    const int tid = threadIdx.x, wave = tid >> 6, lane = tid & 63;
    const int ln = lane & 31, hh = lane >> 5;
    const int bh = blockIdx.y, b = bh >> 4, head = bh & 15;
    const bf16* __restrict__ Kb  = K  + (size_t)bh * (2112 * 64);
    const bf16* __restrict__ Vtb = VT + (size_t)bh * (64 * 2112);
    const int qg = blockIdx.x * 128 + wave * 32 + ln;
    const int nkeys = nk[b];
    const int send = ((nkeys + 63) >> 6) << 6;

    bf16x8 qf[4];
#pragma unroll
    for (int kt = 0; kt < 4; ++kt)
        qf[kt] = *(const bf16x8*)&Q[((size_t)bh * 2048 + qg) * 64 + kt * 16 + hh * 8];

    float l_r = 0.f;
    f32x16 acc[2];
#pragma unroll
    for (int r = 0; r < 16; ++r) { acc[0][r] = 0.f; acc[1][r] = 0.f; }

    const int ks_s = tid >> 3, ks_c = (tid & 7) * 8;
    const int vd = tid >> 3, v8 = tid & 7, vs = v8 * 8;
    const int vcb = (v8 >> 1) * 16 + ((v8 & 1) ? 4 : 0);   // permuted col base

    bf16x8 kr0, kr1, vr0, vr1;
    kr0 = *(const bf16x8*)&Kb[(size_t)ks_s * 64 + ks_c];
    kr1 = *(const bf16x8*)&Kb[(size_t)(ks_s + 32) * 64 + ks_c];
    vr0 = *(const bf16x8*)&Vtb[(size_t)vd * 2112 + vs];
    vr1 = *(const bf16x8*)&Vtb[(size_t)(vd + 32) * 2112 + vs];

    for (int s0 = 0; s0 < send; s0 += 64) {
        __syncthreads();
        *(bf16x8*)&Ks[ks_s * 72 + ks_c]        = kr0;
        *(bf16x8*)&Ks[(ks_s + 32) * 72 + ks_c] = kr1;
        {
            bf16x4 lo, hi;
#pragma unroll
            for (int e = 0; e < 4; ++e) { lo[e] = vr0[e]; hi[e] = vr0[4 + e]; }
            *(bf16x4*)&Vt[vd * 72 + vcb]     = lo;
            *(bf16x4*)&Vt[vd * 72 + vcb + 8] = hi;
#pragma unroll
            for (int e = 0; e < 4; ++e) { lo[e] = vr1[e]; hi[e] = vr1[4 + e]; }
            *(bf16x4*)&Vt[(vd + 32) * 72 + vcb]     = lo;
            *(bf16x4*)&Vt[(vd + 32) * 72 + vcb + 8] = hi;
        }
        __syncthreads();

        if (s0 + 64 < send) {
            const int sn = s0 + 64;
            kr0 = *(const bf16x8*)&Kb[(size_t)(sn + ks_s) * 64 + ks_c];
            kr1 = *(const bf16x8*)&Kb[(size_t)(sn + ks_s + 32) * 64 + ks_c];
            vr0 = *(const bf16x8*)&Vtb[(size_t)vd * 2112 + sn + vs];
            vr1 = *(const bf16x8*)&Vtb[(size_t)(vd + 32) * 2112 + sn + vs];
        }

        // ---- S^T = K * Q^T ----
        f32x16 sc[2];
#pragma unroll
        for (int ts = 0; ts < 2; ++ts) {
            f32x16 s16;
#pragma unroll
            for (int r = 0; r < 16; ++r) s16[r] = 0.f;
#pragma unroll
            for (int kt = 0; kt < 4; ++kt) {
                bf16x8 kf = *(const bf16x8*)&Ks[(ts * 32 + ln) * 72 + kt * 16 + hh * 8];
                s16 = MFMA32(kf, qf[kt], s16);
            }
            sc[ts] = s16;
        }

        // ---- exp2 + pack P into register B-fragments (sigma order) ----
        float rs = 0.f;
        bf16x8 pf[4];
        if (s0 + 64 <= nkeys) {
#pragma unroll
            for (int ts = 0; ts < 2; ++ts)
#pragma unroll
                for (int rg = 0; rg < 4; ++rg)
#pragma unroll
                    for (int i = 0; i < 4; ++i) {
                        float p = __builtin_amdgcn_exp2f(sc[ts][rg * 4 + i] - LOGBIAS);
                        rs += p;
                        pf[ts * 2 + (rg >> 1)][(rg & 1) * 4 + i] = (bf16)p;
                    }
        } else {
#pragma unroll
            for (int ts = 0; ts < 2; ++ts)
#pragma unroll
                for (int rg = 0; rg < 4; ++rg)
#pragma unroll
                    for (int i = 0; i < 4; ++i) {
                        int key = s0 + ts * 32 + rg * 8 + hh * 4 + i;
                        float add = (key < nkeys) ? -LOGBIAS : -1e30f;
                        float p = __builtin_amdgcn_exp2f(sc[ts][rg * 4 + i] + add);
                        rs += p;
                        pf[ts * 2 + (rg >> 1)][(rg & 1) * 4 + i] = (bf16)p;
                    }
        }
        l_r += rs;

        // ---- O^T += V^T * P (permuted k) ----
#pragma unroll
        for (int st = 0; st < 4; ++st) {
            bf16x8 a0 = *(const bf16x8*)&Vt[ln * 72 + st * 16 + hh * 8];
            acc[0] = MFMA32(a0, pf[st], acc[0]);
            bf16x8 a1 = *(const bf16x8*)&Vt[(32 + ln) * 72 + st * 16 + hh * 8];
            acc[1] = MFMA32(a1, pf[st], acc[1]);
        }
    }

    // ---- epilogue: normalize, transpose via smem scratch, store ----
    __syncthreads();                 // all waves done with Ks/Vt
    l_r += __shfl_xor(l_r, 32);
    float inv = 1.0f / l_r;
    bf16* scratch = smem + wave * (32 * 72);
#pragma unroll
    for (int td = 0; td < 2; ++td)
#pragma unroll
        for (int rg = 0; rg < 4; ++rg) {
            bf16x4 ob;
#pragma unroll
            for (int i = 0; i < 4; ++i) ob[i] = (bf16)(acc[td][rg * 4 + i] * inv);
            *(bf16x4*)&scratch[ln * 72 + td * 32 + rg * 8 + hh * 4] = ob;
        }
    __builtin_amdgcn_s_waitcnt(0xC07F);   // lgkmcnt(0): own-wave scratch visible
    const int orow = lane >> 3, oc = (lane & 7) * 8;
#pragma unroll
    for (int pass = 0; pass < 4; ++pass) {
        int ml = pass * 8 + orow;
        bf16x8 ov = *(const bf16x8*)&scratch[ml * 72 + oc];
        int qrow = blockIdx.x * 128 + wave * 32 + ml;
        *(bf16x8*)&O[((size_t)b * 2048 + qrow) * 1024 + head * 64 + oc] = ov;
    }
}

// ---------------------------------------------------------------------------
// Output projection: out[m,n] = sum_k A[m,k]*Wo[n,k] + bo[n]; bf16 in, f32 out
// ---------------------------------------------------------------------------
__global__ __launch_bounds__(256) void out_proj_gemm(
    const bf16* __restrict__ A, const bf16* __restrict__ W,
    const float* __restrict__ bias, float* __restrict__ out)
{
    __shared__ bf16 As[128 * 32];
    __shared__ bf16 Bs[128 * 32];
    const int m0 = blockIdx.x * 128, n0 = blockIdx.y * 128;
    const int tid = threadIdx.x, lane = tid & 63, wave = tid >> 6;
    const int ln = lane & 15, quad = lane >> 4;
    const int wr = (wave >> 1) * 64, wc = (wave & 1) * 64;
    const int srow = wave * 32 + (lane >> 2);
    const int scol = (lane & 3) * 8;

    const f32x4 z4 = {0.f, 0.f, 0.f, 0.f};
    f32x4 acc[4][4];
#pragma unroll
    for (int i = 0; i < 4; ++i)
#pragma unroll
        for (int j = 0; j < 4; ++j) acc[i][j] = z4;

    for (int k0 = 0; k0 < 1024; k0 += 32) {
        __syncthreads();
        gl_lds16(&A[(size_t)(m0 + srow) * 1024 + k0 + scol],      &As[(wave * 32) * 32]);
        gl_lds16(&A[(size_t)(m0 + srow + 16) * 1024 + k0 + scol], &As[(wave * 32 + 16) * 32]);
        gl_lds16(&W[(size_t)(n0 + srow) * 1024 + k0 + scol],      &Bs[(wave * 32) * 32]);
        gl_lds16(&W[(size_t)(n0 + srow + 16) * 1024 + k0 + scol], &Bs[(wave * 32 + 16) * 32]);
        __syncthreads();
        bf16x8 af[4], bfr[4];
#pragma unroll
        for (int i = 0; i < 4; ++i) af[i]  = *(const bf16x8*)&As[(wr + i * 16 + ln) * 32 + quad * 8];
#pragma unroll
        for (int j = 0; j < 4; ++j) bfr[j] = *(const bf16x8*)&Bs[(wc + j * 16 + ln) * 32 + quad * 8];
#pragma unroll
        for (int i = 0; i < 4; ++i)
#pragma unroll
            for (int j = 0; j < 4; ++j)
                acc[i][j] = MFMA16(af[i], bfr[j], acc[i][j]);
    }

#pragma unroll
    for (int j = 0; j < 4; ++j) {
        const int n = n0 + wc + j * 16 + ln;
        const float bb = bias[n];
#pragma unroll
        for (int i = 0; i < 4; ++i) {
#pragma unroll
            for (int r = 0; r < 4; ++r) {
                int m = m0 + wr + i * 16 + quad * 4 + r;
                out[(size_t)m * 1024 + n] = acc[i][j][r] + bb;
            }
        }
    }
}

// ---------------------------------------------------------------------------
extern "C" void kernel_launch(void* const* d_in, const int* in_sizes, int n_in,
                              void* d_out, int out_size, void* d_ws, size_t ws_size,
                              hipStream_t stream)
{
    const float* x    = (const float*)d_in[0];
    const int*   mask = (const int*)d_in[1];
    const float* pk   = (const float*)d_in[2];
    const float* pv   = (const float*)d_in[3];
    const float* Wq   = (const float*)d_in[4];
    const float* bq   = (const float*)d_in[5];
    const float* Wk   = (const float*)d_in[6];
    const float* bk   = (const float*)d_in[7];
    const float* Wv   = (const float*)d_in[8];
    const float* bv   = (const float*)d_in[9];
    const float* Wo   = (const float*)d_in[10];
    const float* bo   = (const float*)d_in[11];
    float* out = (float*)d_out;

    bf16* xb    = (bf16*)d_ws;                   // [8192,1024] bf16
    bf16* wb    = xb + (size_t)8388608;          // 4 x [1024,1024] bf16
    bf16* q_ws  = wb + (size_t)4194304;          // [B,H,T,D]
    bf16* k_ws  = q_ws + (size_t)8388608;        // [B,H,S,D] compacted
    bf16* vt_ws = k_ws + (size_t)8650752;        // [B,H,D,S] compacted V^T
    int*  ridx  = (int*)(vt_ws + (size_t)8650752);  // [B,T]
    int*  nkv   = ridx + 4 * 2048;                  // [B]
    bf16* a_ws  = xb;   // alias: xb consumed by projections before attn writes

    prep<<<dim3(12548), 256, 0, stream>>>(x, Wq, Wk, Wv, Wo, pk, pv, mask,
                                          xb, wb, k_ws, vt_ws, ridx, nkv);
    proj_gemm<<<dim3(1536), 256, 0, stream>>>(xb, wb, bq, bk, bv, ridx, nkv,
                                              q_ws, k_ws, vt_ws);
    attn_kernel<<<dim3(16, 64), 256, 0, stream>>>(q_ws, k_ws, vt_ws, nkv, a_ws);
    out_proj_gemm<<<dim3(64, 8), 256, 0, stream>>>(a_ws, wb + (size_t)3 * 1048576,
                                                   bo, out);
}